// Round 1
// baseline (1661.436 us; speedup 1.0000x reference)
//
#include <hip/hip_runtime.h>
#include <hip/hip_bf16.h>
#include <cstddef>

#define NPIX 262144   // 512*512
typedef __hip_bfloat16 bf16;

// ---------------- zero init ----------------
__global__ void zero_kernel(float* out, float* stats, float* pooled){
  int i = blockIdx.x*256 + threadIdx.x;
  if (i < 262147) out[i] = 0.f;            // grid + log_prob + entropy + value
  if (i < 68)  stats[i]  = 0.f;            // 12 + 24 + 32 group sums/sumsq
  if (i < 128) pooled[i] = 0.f;
}

// ---------------- conv1: 14 -> 48, fp32 input ----------------
// tile 32x32, 256 threads, 4 px/thread, OCB=24 (blockIdx.y in 0..1), CCH=7
__launch_bounds__(256,2)
__global__ void conv1_kernel(const float* __restrict__ x, const float* __restrict__ w,
                             const float* __restrict__ b, bf16* __restrict__ out){
  __shared__ float sIn[7*34*34];
  __shared__ float sW[7*9*24];
  const int tid = threadIdx.x;
  const int tx = tid & 31, ty = tid >> 5;
  const int tileX = (blockIdx.x & 15)*32, tileY = (blockIdx.x >> 4)*32;
  const int ocg = blockIdx.y;
  float acc[24*4];
  #pragma unroll
  for (int o=0;o<24;o++){ float bv=b[ocg*24+o];
    acc[o*4]=bv; acc[o*4+1]=bv; acc[o*4+2]=bv; acc[o*4+3]=bv; }
  #pragma unroll 1
  for (int c0=0;c0<14;c0+=7){
    for (int idx=tid; idx<7*1156; idx+=256){
      int c = idx/1156, rem = idx - c*1156;
      int r = rem/34, col = rem - r*34;
      int gy = tileY + r - 1, gx = tileX + col - 1;
      float v = 0.f;
      if ((unsigned)gy < 512u && (unsigned)gx < 512u)
        v = x[(size_t)(c0+c)*NPIX + gy*512 + gx];
      sIn[idx] = v;
    }
    for (int idx=tid; idx<7*9*24; idx+=256){
      int k = idx/24, o = idx - k*24;
      int c = k/9, t = k - c*9;
      sW[idx] = w[((size_t)(ocg*24+o)*14 + (c0+c))*9 + t];
    }
    __syncthreads();
    #pragma unroll 1
    for (int c=0;c<7;c++){
      #pragma unroll
      for (int ky=0;ky<3;ky++){
        #pragma unroll
        for (int kx=0;kx<3;kx++){
          float v0 = sIn[c*1156 + (ty   +ky)*34 + tx+kx];
          float v1 = sIn[c*1156 + (ty+ 8+ky)*34 + tx+kx];
          float v2 = sIn[c*1156 + (ty+16+ky)*34 + tx+kx];
          float v3 = sIn[c*1156 + (ty+24+ky)*34 + tx+kx];
          const float* wp = &sW[(c*9+ky*3+kx)*24];
          #pragma unroll
          for (int o=0;o<24;o++){
            float wv = wp[o];
            acc[o*4]   += v0*wv;
            acc[o*4+1] += v1*wv;
            acc[o*4+2] += v2*wv;
            acc[o*4+3] += v3*wv;
          }
        }
      }
    }
    __syncthreads();
  }
  #pragma unroll
  for (int o=0;o<24;o++){
    size_t base = (size_t)(ocg*24+o)*NPIX;
    #pragma unroll
    for (int q=0;q<4;q++)
      out[base + (tileY+ty+q*8)*512 + tileX+tx] = __float2bfloat16(acc[o*4+q]);
  }
}

// ---------------- conv2/conv3: bf16 raw input + fused GN(A,B)+ReLU on load ----------------
// tile 32x32, 256 threads, 4 px/thread, OCB=32 per blockIdx.y, CCH=8
template<int CIN>
__launch_bounds__(256,2)
__global__ void conv_bf16_kernel(const bf16* __restrict__ in, const float* __restrict__ nA,
                                 const float* __restrict__ nB, const float* __restrict__ w,
                                 const float* __restrict__ b, bf16* __restrict__ out){
  __shared__ float sIn[8*34*34];
  __shared__ float sW[8*9*32];
  const int tid = threadIdx.x;
  const int tx = tid & 31, ty = tid >> 5;
  const int tileX = (blockIdx.x & 15)*32, tileY = (blockIdx.x >> 4)*32;
  const int ocg = blockIdx.y;
  float acc[32*4];
  #pragma unroll
  for (int o=0;o<32;o++){ float bv=b[ocg*32+o];
    acc[o*4]=bv; acc[o*4+1]=bv; acc[o*4+2]=bv; acc[o*4+3]=bv; }
  #pragma unroll 1
  for (int c0=0;c0<CIN;c0+=8){
    for (int idx=tid; idx<8*1156; idx+=256){
      int c = idx/1156, rem = idx - c*1156;
      int r = rem/34, col = rem - r*34;
      int gy = tileY + r - 1, gx = tileX + col - 1;
      float v = 0.f;
      if ((unsigned)gy < 512u && (unsigned)gx < 512u){
        float xv = __bfloat162float(in[(size_t)(c0+c)*NPIX + gy*512 + gx]);
        v = fmaxf(xv*nA[c0+c] + nB[c0+c], 0.f);
      }
      sIn[idx] = v;
    }
    for (int idx=tid; idx<8*9*32; idx+=256){
      int k = idx >> 5, o = idx & 31;
      int c = k/9, t = k - c*9;
      sW[idx] = w[((size_t)(ocg*32+o)*CIN + (c0+c))*9 + t];
    }
    __syncthreads();
    #pragma unroll 1
    for (int c=0;c<8;c++){
      #pragma unroll
      for (int ky=0;ky<3;ky++){
        #pragma unroll
        for (int kx=0;kx<3;kx++){
          float v0 = sIn[c*1156 + (ty   +ky)*34 + tx+kx];
          float v1 = sIn[c*1156 + (ty+ 8+ky)*34 + tx+kx];
          float v2 = sIn[c*1156 + (ty+16+ky)*34 + tx+kx];
          float v3 = sIn[c*1156 + (ty+24+ky)*34 + tx+kx];
          const float* wp = &sW[(c*9+ky*3+kx)*32];
          #pragma unroll
          for (int o=0;o<32;o++){
            float wv = wp[o];
            acc[o*4]   += v0*wv;
            acc[o*4+1] += v1*wv;
            acc[o*4+2] += v2*wv;
            acc[o*4+3] += v3*wv;
          }
        }
      }
    }
    __syncthreads();
  }
  #pragma unroll
  for (int o=0;o<32;o++){
    size_t base = (size_t)(ocg*32+o)*NPIX;
    #pragma unroll
    for (int q=0;q<4;q++)
      out[base + (tileY+ty+q*8)*512 + tileX+tx] = __float2bfloat16(acc[o*4+q]);
  }
}

// ---------------- per-group stats (sum, sumsq) over raw conv output ----------------
// blockIdx.x = c*4 + quarter; group = c>>3 (8 channels per group for all layers)
__global__ void stats_kernel(const bf16* __restrict__ buf, float* __restrict__ stats){
  int c = blockIdx.x >> 2, q = blockIdx.x & 3;
  const uint4* p = (const uint4*)(buf + (size_t)c*NPIX + q*65536);
  float s=0.f, s2=0.f;
  for (int i=threadIdx.x; i<8192; i+=256){
    uint4 v = p[i];
    unsigned u0=v.x,u1=v.y,u2=v.z,u3=v.w;
    unsigned uu[4]={u0,u1,u2,u3};
    #pragma unroll
    for (int j=0;j<4;j++){
      float a = __uint_as_float(uu[j]<<16);
      float d = __uint_as_float(uu[j]&0xffff0000u);
      s  += a + d;
      s2 += a*a + d*d;
    }
  }
  #pragma unroll
  for (int off=32; off; off>>=1){ s += __shfl_xor(s, off); s2 += __shfl_xor(s2, off); }
  __shared__ float rs[8];
  if ((threadIdx.x & 63)==0){ rs[(threadIdx.x>>6)*2]=s; rs[(threadIdx.x>>6)*2+1]=s2; }
  __syncthreads();
  if (threadIdx.x==0){
    float S=rs[0]+rs[2]+rs[4]+rs[6], S2=rs[1]+rs[3]+rs[5]+rs[7];
    atomicAdd(&stats[(c>>3)*2],   S);
    atomicAdd(&stats[(c>>3)*2+1], S2);
  }
}

// ---------------- per-channel affine from group stats ----------------
__global__ void normparam_kernel(const float* __restrict__ stats, const float* __restrict__ gamma,
                                 const float* __restrict__ beta, float* __restrict__ nA,
                                 float* __restrict__ nB, int C){
  int c = threadIdx.x;
  if (c >= C) return;
  int g = c >> 3;
  const float invN = 1.f/2097152.f;   // 8 channels * 262144
  float m = stats[g*2]*invN;
  float v = stats[g*2+1]*invN - m*m;
  float inv = rsqrtf(v + 1e-5f);
  float A = inv*gamma[c];
  nA[c] = A;
  nB[c] = beta[c] - m*A;
}

// ---------------- global average pool of normalized+ReLU f ----------------
__global__ void pool_kernel(const bf16* __restrict__ buf, const float* __restrict__ nA,
                            const float* __restrict__ nB, float* __restrict__ pooled){
  int c = blockIdx.x >> 2, q = blockIdx.x & 3;
  float A = nA[c], B = nB[c];
  const uint4* p = (const uint4*)(buf + (size_t)c*NPIX + q*65536);
  float s = 0.f;
  for (int i=threadIdx.x; i<8192; i+=256){
    uint4 v = p[i];
    unsigned uu[4]={v.x,v.y,v.z,v.w};
    #pragma unroll
    for (int j=0;j<4;j++){
      s += fmaxf(__uint_as_float(uu[j]<<16)*A + B, 0.f);
      s += fmaxf(__uint_as_float(uu[j]&0xffff0000u)*A + B, 0.f);
    }
  }
  #pragma unroll
  for (int off=32; off; off>>=1) s += __shfl_xor(s, off);
  __shared__ float rs[4];
  if ((threadIdx.x&63)==0) rs[threadIdx.x>>6]=s;
  __syncthreads();
  if (threadIdx.x==0) atomicAdd(&pooled[c], rs[0]+rs[1]+rs[2]+rs[3]);
}

// ---------------- value head MLP ----------------
__global__ void value_kernel(const float* __restrict__ pooled, const float* __restrict__ vw1,
                             const float* __restrict__ vb1, const float* __restrict__ vw2,
                             const float* __restrict__ vb2, float* __restrict__ out){
  int t = threadIdx.x;   // 64 threads
  float h = vb1[t];
  const float invN = 1.f/262144.f;
  for (int c=0;c<128;c++) h += (pooled[c]*invN)*vw1[c*64+t];
  h = fmaxf(h, 0.f);
  float v = h*vw2[t];
  #pragma unroll
  for (int off=32; off; off>>=1) v += __shfl_xor(v, off);
  if (t==0) out[262146] = v + vb2[0];
}

// ---------------- patch gather + FC1 (1152 -> 256), 8 cells per block ----------------
__launch_bounds__(256)
__global__ void gather_fc1_kernel(const bf16* __restrict__ f, const float* __restrict__ nA,
                                  const float* __restrict__ nB, const int* __restrict__ cell_i,
                                  const int* __restrict__ cell_j, const float* __restrict__ fw1,
                                  const float* __restrict__ fb1, float* __restrict__ h1){
  __shared__ float sF[8*1152];
  const int tid = threadIdx.x;
  const int cellBase = blockIdx.x*8;
  #pragma unroll 1
  for (int lc=0; lc<8; lc++){
    int ci = cell_i[cellBase+lc], cj = cell_j[cellBase+lc];
    for (int idx=tid; idx<1152; idx+=256){
      int c = idx/9, rr = idx - c*9;
      int r = rr/3, col = rr - r*3;
      int y = ci-1+r, x = cj-1+col;
      float v = 0.f;
      if ((unsigned)y < 512u && (unsigned)x < 512u){
        float xv = __bfloat162float(f[(size_t)c*NPIX + y*512 + x]);
        v = fmaxf(xv*nA[c] + nB[c], 0.f);
      }
      sF[lc*1152+idx] = v;
    }
  }
  __syncthreads();
  float acc[8];
  float bv = fb1[tid];
  #pragma unroll
  for (int lc=0;lc<8;lc++) acc[lc]=bv;
  #pragma unroll 4
  for (int k=0;k<1152;k++){
    float wv = fw1[(size_t)k*256 + tid];
    #pragma unroll
    for (int lc=0;lc<8;lc++) acc[lc] += sF[lc*1152+k]*wv;
  }
  #pragma unroll
  for (int lc=0;lc<8;lc++)
    h1[(size_t)(cellBase+lc)*256 + tid] = fmaxf(acc[lc], 0.f);
}

// ---------------- FC2 (256->128) + 3 heads + log_prob/entropy + scatter ----------------
__launch_bounds__(256)
__global__ void fc2_heads_kernel(const float* __restrict__ h1, const float* __restrict__ fw2,
                                 const float* __restrict__ fb2, const float* __restrict__ bw,
                                 const float* __restrict__ bb, const float* __restrict__ iw,
                                 const float* __restrict__ ib, const float* __restrict__ tw,
                                 const float* __restrict__ tb, const int* __restrict__ cell_i,
                                 const int* __restrict__ cell_j, const int* __restrict__ action,
                                 float* __restrict__ out){
  __shared__ float sH[8*256];
  __shared__ float sS[8*128];
  __shared__ float sRed[2];
  const int tid = threadIdx.x;
  const int cellBase = blockIdx.x*8;
  if (tid < 2) sRed[tid] = 0.f;
  for (int idx=tid; idx<2048; idx+=256) sH[idx] = h1[(size_t)cellBase*256 + idx];
  __syncthreads();
  const int j = tid & 127, half = tid >> 7;
  float acc[4];
  float bv = fb2[j];
  #pragma unroll
  for (int i=0;i<4;i++) acc[i]=bv;
  #pragma unroll 4
  for (int k=0;k<256;k++){
    float wv = fw2[k*128 + j];
    #pragma unroll
    for (int i=0;i<4;i++) acc[i] += sH[(half*4+i)*256 + k]*wv;
  }
  #pragma unroll
  for (int i=0;i<4;i++) sS[(half*4+i)*128 + j] = fmaxf(acc[i], 0.f);
  __syncthreads();
  if (tid < 96){
    int lc = tid/12, jj = tid - lc*12;
    int which = jj >> 2, o = jj & 3;
    const float* W  = (which==0) ? bw : (which==1 ? iw : tw);
    const float* Bp = (which==0) ? bb : (which==1 ? ib : tb);
    float d = Bp[o];
    for (int k=0;k<128;k++) d += sS[lc*128+k]*W[k*4+o];
    int cell = cellBase + lc;
    if (which == 1){
      out[262147 + cell*4 + o] = d;
    } else if (which == 2){
      out[262147 + 32768 + cell*4 + o] = d;
    } else {
      float p = 1.f/(1.f + __expf(-d));
      p = fminf(fmaxf(p, 1e-7f), 1.f - 1e-7f);
      int a = action[cell*4 + o];
      float lp  = a ? __logf(p) : __logf(1.f-p);
      float ent = -(p*__logf(p) + (1.f-p)*__logf(1.f-p));
      atomicAdd(&sRed[0], lp);
      atomicAdd(&sRed[1], ent);
      if (a){
        const int di[4] = {-1,0,1,0};
        const int dj[4] = {0,1,0,-1};
        int ni = cell_i[cell] + di[o];
        int nj = cell_j[cell] + dj[o];
        if ((unsigned)ni < 512u && (unsigned)nj < 512u)
          out[ni*512 + nj] = 1.0f;
      }
    }
  }
  __syncthreads();
  if (tid==0){
    atomicAdd(&out[262144], sRed[0]);
    atomicAdd(&out[262145], sRed[1]);
  }
}

extern "C" void kernel_launch(void* const* d_in, const int* in_sizes, int n_in,
                              void* d_out, int out_size, void* d_ws, size_t ws_size,
                              hipStream_t stream) {
  (void)in_sizes; (void)n_in; (void)out_size; (void)ws_size;
  const float* x      = (const float*)d_in[0];
  const int*  cell_i  = (const int*)d_in[1];
  const int*  cell_j  = (const int*)d_in[2];
  const int*  action  = (const int*)d_in[3];
  const float* w1 = (const float*)d_in[4];  const float* b1 = (const float*)d_in[5];
  const float* g1 = (const float*)d_in[6];  const float* be1= (const float*)d_in[7];
  const float* w2 = (const float*)d_in[8];  const float* b2 = (const float*)d_in[9];
  const float* g2 = (const float*)d_in[10]; const float* be2= (const float*)d_in[11];
  const float* w3 = (const float*)d_in[12]; const float* b3 = (const float*)d_in[13];
  const float* g3 = (const float*)d_in[14]; const float* be3= (const float*)d_in[15];
  const float* fw1= (const float*)d_in[16]; const float* fb1= (const float*)d_in[17];
  const float* fw2= (const float*)d_in[18]; const float* fb2= (const float*)d_in[19];
  const float* bw = (const float*)d_in[20]; const float* bb = (const float*)d_in[21];
  const float* iw = (const float*)d_in[22]; const float* ib = (const float*)d_in[23];
  const float* tw = (const float*)d_in[24]; const float* tb = (const float*)d_in[25];
  const float* vw1= (const float*)d_in[26]; const float* vb1= (const float*)d_in[27];
  const float* vw2= (const float*)d_in[28]; const float* vb2= (const float*)d_in[29];

  float* out = (float*)d_out;
  char* ws = (char*)d_ws;
  // workspace layout (bytes)
  bf16* buf1 = (bf16*)(ws + 0);            // 48*262144*2  = 25165824
  bf16* buf2 = (bf16*)(ws + 25165824);     // 96*262144*2  = 50331648
  bf16* bufF = (bf16*)(ws + 75497472);     // 128*262144*2 = 67108864
  float* stats  = (float*)(ws + 142606336);// 68 floats (12+24+32)
  float* norm   = stats + 256;             // A1(48) B1(48) A2(96) B2(96) A3(128) B3(128)
  float* A1 = norm,       *B1 = norm+48;
  float* A2 = norm+96,    *B2 = norm+192;
  float* A3 = norm+288,   *B3 = norm+416;
  float* pooled = norm + 1024;             // 128 floats
  float* h1 = (float*)ws;                  // reuse buf1 region (conv1 output dead by then)

  zero_kernel<<<1025, 256, 0, stream>>>(out, stats, pooled);

  conv1_kernel<<<dim3(256,2), 256, 0, stream>>>(x, w1, b1, buf1);
  stats_kernel<<<48*4, 256, 0, stream>>>(buf1, stats + 0);
  normparam_kernel<<<1, 128, 0, stream>>>(stats + 0, g1, be1, A1, B1, 48);

  conv_bf16_kernel<48><<<dim3(256,3), 256, 0, stream>>>(buf1, A1, B1, w2, b2, buf2);
  stats_kernel<<<96*4, 256, 0, stream>>>(buf2, stats + 12);
  normparam_kernel<<<1, 128, 0, stream>>>(stats + 12, g2, be2, A2, B2, 96);

  conv_bf16_kernel<96><<<dim3(256,4), 256, 0, stream>>>(buf2, A2, B2, w3, b3, bufF);
  stats_kernel<<<128*4, 256, 0, stream>>>(bufF, stats + 36);
  normparam_kernel<<<1, 128, 0, stream>>>(stats + 36, g3, be3, A3, B3, 128);

  pool_kernel<<<128*4, 256, 0, stream>>>(bufF, A3, B3, pooled);
  value_kernel<<<1, 64, 0, stream>>>(pooled, vw1, vb1, vw2, vb2, out);

  gather_fc1_kernel<<<1024, 256, 0, stream>>>(bufF, A3, B3, cell_i, cell_j, fw1, fb1, h1);
  fc2_heads_kernel<<<1024, 256, 0, stream>>>(h1, fw2, fb2, bw, bb, iw, ib, tw, tb,
                                             cell_i, cell_j, action, out);
}

// Round 2
// 586.636 us; speedup vs baseline: 2.8321x; 2.8321x over previous
//
#include <hip/hip_runtime.h>
#include <hip/hip_bf16.h>
#include <cstddef>

#define NPIX 262144   // 512*512
#define PW 514        // padded width/height
typedef __hip_bfloat16 bf16;
typedef __attribute__((ext_vector_type(8))) short short8;
typedef __attribute__((ext_vector_type(4))) float f32x4;

__device__ inline unsigned short f2bfu(float f){
  __hip_bfloat16 h = __float2bfloat16(f);
  return *(reinterpret_cast<unsigned short*>(&h));
}

// ---------------- zero init ----------------
__global__ void zero_kernel(float* out, float* stats, float* pooled){
  int i = blockIdx.x*256 + threadIdx.x;
  if (i < 262147) out[i] = 0.f;            // grid + log_prob + entropy + value
  if (i < 68)  stats[i]  = 0.f;            // 12 + 24 + 32 group sums/sumsq
  if (i < 128) pooled[i] = 0.f;
}

// ---------------- zero the 1-px border of a padded NHWC buffer ----------------
template<int C>
__global__ void border_zero_kernel(bf16* buf){
  constexpr int NCH = C/8;
  int idx = blockIdx.x*256 + threadIdx.x;
  if (idx >= 2052*NCH) return;
  int cc = idx % NCH; int p = idx / NCH;
  int r, c;
  if (p < 514){ r = 0; c = p; }
  else if (p < 1028){ r = 513; c = p - 514; }
  else if (p < 1540){ r = p - 1027; c = 0; }
  else { r = p - 1539; c = 513; }
  *(uint4*)(buf + ((size_t)r*PW + c)*C + cc*8) = make_uint4(0,0,0,0);
}

// ---------------- weight transform: OIHW fp32 -> [tap][cc32][oc][c'] bf16 (zero-pad ic) ----------------
template<int OC, int IC, int NCC>
__global__ void wtrans_kernel(const float* __restrict__ w, bf16* __restrict__ wT){
  constexpr int TOT = 9*NCC*OC*32;
  int idx = blockIdx.x*256 + threadIdx.x;
  if (idx >= TOT) return;
  int cp = idx & 31; int rest = idx >> 5;
  int oc = rest % OC; rest /= OC;
  int cc = rest % NCC; int tap = rest / NCC;
  int ic = cc*32 + cp;
  float v = (ic < IC) ? w[(oc*IC + ic)*9 + tap] : 0.f;
  wT[idx] = __float2bfloat16(v);
}

// ---------------- conv1: 14 -> 48, fp32 NCHW input -> raw bf16 padded NHWC ----------------
__launch_bounds__(256,2)
__global__ void conv1_kernel(const float* __restrict__ x, const float* __restrict__ w,
                             const float* __restrict__ b, bf16* __restrict__ out){
  __shared__ float sIn[7*34*34];
  __shared__ float sW[7*9*24];
  const int tid = threadIdx.x;
  const int tx = tid & 31, ty = tid >> 5;
  const int tileX = (blockIdx.x & 15)*32, tileY = (blockIdx.x >> 4)*32;
  const int ocg = blockIdx.y;
  float acc[24*4];
  #pragma unroll
  for (int o=0;o<24;o++){ float bv=b[ocg*24+o];
    acc[o*4]=bv; acc[o*4+1]=bv; acc[o*4+2]=bv; acc[o*4+3]=bv; }
  #pragma unroll 1
  for (int c0=0;c0<14;c0+=7){
    for (int idx=tid; idx<7*1156; idx+=256){
      int c = idx/1156, rem = idx - c*1156;
      int r = rem/34, col = rem - r*34;
      int gy = tileY + r - 1, gx = tileX + col - 1;
      float v = 0.f;
      if ((unsigned)gy < 512u && (unsigned)gx < 512u)
        v = x[(size_t)(c0+c)*NPIX + gy*512 + gx];
      sIn[idx] = v;
    }
    for (int idx=tid; idx<7*9*24; idx+=256){
      int k = idx/24, o = idx - k*24;
      int c = k/9, t = k - c*9;
      sW[idx] = w[((size_t)(ocg*24+o)*14 + (c0+c))*9 + t];
    }
    __syncthreads();
    #pragma unroll 1
    for (int c=0;c<7;c++){
      #pragma unroll
      for (int ky=0;ky<3;ky++){
        #pragma unroll
        for (int kx=0;kx<3;kx++){
          float v0 = sIn[c*1156 + (ty   +ky)*34 + tx+kx];
          float v1 = sIn[c*1156 + (ty+ 8+ky)*34 + tx+kx];
          float v2 = sIn[c*1156 + (ty+16+ky)*34 + tx+kx];
          float v3 = sIn[c*1156 + (ty+24+ky)*34 + tx+kx];
          const float* wp = &sW[(c*9+ky*3+kx)*24];
          #pragma unroll
          for (int o=0;o<24;o++){
            float wv = wp[o];
            acc[o*4]   += v0*wv;
            acc[o*4+1] += v1*wv;
            acc[o*4+2] += v2*wv;
            acc[o*4+3] += v3*wv;
          }
        }
      }
    }
    __syncthreads();
  }
  #pragma unroll
  for (int q=0;q<4;q++){
    size_t base = ((size_t)(tileY+ty+q*8+1)*PW + tileX+tx+1)*48 + ocg*24;
    #pragma unroll
    for (int og=0;og<6;og++){
      uint2 pk;
      pk.x = (unsigned)f2bfu(acc[(og*4+0)*4+q]) | ((unsigned)f2bfu(acc[(og*4+1)*4+q])<<16);
      pk.y = (unsigned)f2bfu(acc[(og*4+2)*4+q]) | ((unsigned)f2bfu(acc[(og*4+3)*4+q])<<16);
      *(uint2*)(out + base + og*4) = pk;
    }
  }
}

// ---------------- MFMA implicit-GEMM conv (3x3 SAME), padded NHWC in/out ----------------
// block: 16x16 px tile, 4 waves = 2 oc-groups x 2 px-groups; wave: OCT oc-tiles x 8 px-tiles
template<int IC, int NCC, int OCT, int OC>
__launch_bounds__(256, 2)
__global__ void conv_mfma_kernel(const bf16* __restrict__ in, const bf16* __restrict__ wT,
                                 const float* __restrict__ bias, bf16* __restrict__ out){
  constexpr int ICP = 40;                 // LDS pixel stride (bf16): 20 dwords -> 2-way conflicts only
  __shared__ bf16 sIn[18*18*ICP];
  const int tid  = threadIdx.x;
  const int lane = tid & 63, wave = tid >> 6;
  const int quad = lane >> 4, l15 = lane & 15;
  const int ocg = wave >> 1, pxg = wave & 1;
  const int tileX = (blockIdx.x & 31) * 16, tileY = (blockIdx.x >> 5) * 16;
  const int ocbase = ocg * (OCT*16);

  f32x4 acc[OCT][8];
  #pragma unroll
  for (int t = 0; t < OCT; ++t){
    f32x4 bv = *(const f32x4*)(bias + ocbase + t*16 + quad*4);
    #pragma unroll
    for (int s = 0; s < 8; ++s) acc[t][s] = bv;
  }

  #pragma unroll 1
  for (int cr = 0; cr < NCC; ++cr){
    __syncthreads();
    // stage channels [cr*32, cr*32+32) of the 18x18 halo patch (zero-fill past IC)
    #pragma unroll 1
    for (int idx = tid; idx < 18*18*4; idx += 256){
      int cc = idx & 3; int p = idx >> 2;
      int row = p / 18, col = p - row*18;
      uint4 v = make_uint4(0,0,0,0);
      if (cr*32 + cc*8 < IC)
        v = *(const uint4*)(in + ((size_t)(tileY+row)*PW + tileX+col)*IC + cr*32 + cc*8);
      *(uint4*)(&sIn[p*ICP + cc*8]) = v;
    }
    __syncthreads();

    short8 a_cur[OCT], a_nxt[OCT];
    #pragma unroll
    for (int t = 0; t < OCT; ++t)
      a_cur[t] = *(const short8*)(wT + ((size_t)(0*NCC + cr)*OC + ocbase + t*16 + l15)*32 + quad*8);
    #pragma unroll 1
    for (int tap = 0; tap < 9; ++tap){
      if (tap < 8){
        #pragma unroll
        for (int t = 0; t < OCT; ++t)
          a_nxt[t] = *(const short8*)(wT + ((size_t)((tap+1)*NCC + cr)*OC + ocbase + t*16 + l15)*32 + quad*8);
      }
      const int ky = tap/3, kx = tap - ky*3;
      short8 b[8];
      #pragma unroll
      for (int s = 0; s < 8; ++s){
        int py = pxg*8 + s;
        b[s] = *(const short8*)(&sIn[((py+ky)*18 + l15+kx)*ICP + quad*8]);
      }
      #pragma unroll
      for (int s = 0; s < 8; ++s){
        #pragma unroll
        for (int t = 0; t < OCT; ++t)
          acc[t][s] = __builtin_amdgcn_mfma_f32_16x16x32_bf16(a_cur[t], b[s], acc[t][s], 0, 0, 0);
      }
      #pragma unroll
      for (int t = 0; t < OCT; ++t) a_cur[t] = a_nxt[t];
    }
  }

  // epilogue: reg r = oc quad*4+r (contiguous in NHWC) -> pack 4 bf16 = 8B stores
  #pragma unroll
  for (int t = 0; t < OCT; ++t){
    #pragma unroll
    for (int s = 0; s < 8; ++s){
      int py = pxg*8 + s;
      f32x4 v = acc[t][s];
      uint2 pk;
      pk.x = (unsigned)f2bfu(v[0]) | ((unsigned)f2bfu(v[1]) << 16);
      pk.y = (unsigned)f2bfu(v[2]) | ((unsigned)f2bfu(v[3]) << 16);
      size_t off = ((size_t)(tileY+py+1)*PW + (tileX+l15+1))*OC + ocbase + t*16 + quad*4;
      *(uint2*)(out + off) = pk;
    }
  }
}

// ---------------- per-group stats over raw padded NHWC (8 ch per group = 1 uint4) ----------------
template<int C>
__global__ void stats_nhwc_kernel(const bf16* __restrict__ buf, float* __restrict__ stats){
  constexpr int NG = C/8;
  constexpr int S = 256/NG;
  __shared__ float sred[NG*2];
  const int tid = threadIdx.x;
  if (tid < NG*2) sred[tid] = 0.f;
  __syncthreads();
  const int gl = tid % NG, xl = tid / NG;
  float s = 0.f, s2 = 0.f;
  if (xl < S){
    const int y = blockIdx.x;
    for (int x = xl; x < 512; x += S){
      uint4 v = *(const uint4*)(buf + ((size_t)(y+1)*PW + x+1)*C + gl*8);
      unsigned uu[4] = {v.x,v.y,v.z,v.w};
      #pragma unroll
      for (int j = 0; j < 4; ++j){
        float a = __uint_as_float(uu[j]<<16);
        float d = __uint_as_float(uu[j]&0xffff0000u);
        s += a + d; s2 += a*a + d*d;
      }
    }
  }
  atomicAdd(&sred[gl*2], s);
  atomicAdd(&sred[gl*2+1], s2);
  __syncthreads();
  if (tid < NG*2) atomicAdd(&stats[tid], sred[tid]);
}

// ---------------- per-channel affine from group stats ----------------
__global__ void normparam_kernel(const float* __restrict__ stats, const float* __restrict__ gamma,
                                 const float* __restrict__ beta, float* __restrict__ nA,
                                 float* __restrict__ nB, int C){
  int c = threadIdx.x;
  if (c >= C) return;
  int g = c >> 3;
  const float invN = 1.f/2097152.f;   // 8 channels * 262144
  float m = stats[g*2]*invN;
  float v = stats[g*2+1]*invN - m*m;
  float inv = rsqrtf(v + 1e-5f);
  float A = inv*gamma[c];
  nA[c] = A;
  nB[c] = beta[c] - m*A;
}

// ---------------- in-place normalize + ReLU (optionally accumulate global-avg pool) ----------------
template<int C, bool POOL>
__global__ void norm_relu_kernel(bf16* buf, const float* __restrict__ nA, const float* __restrict__ nB,
                                 float* __restrict__ pooled){
  constexpr int NG = C/8;
  constexpr int S = 256/NG;
  __shared__ float sP[C];
  const int tid = threadIdx.x;
  if (POOL){ if (tid < C) sP[tid] = 0.f; __syncthreads(); }
  const int gl = tid % NG, xl = tid / NG;
  float ps[8] = {0,0,0,0,0,0,0,0};
  if (xl < S){
    float A[8], Bv[8];
    #pragma unroll
    for (int j=0;j<8;++j){ A[j]=nA[gl*8+j]; Bv[j]=nB[gl*8+j]; }
    const int y = blockIdx.x;
    for (int x = xl; x < 512; x += S){
      size_t off = ((size_t)(y+1)*PW + x+1)*C + gl*8;
      uint4 v = *(const uint4*)(buf + off);
      unsigned uu[4] = {v.x,v.y,v.z,v.w};
      unsigned ou[4];
      #pragma unroll
      for (int j=0;j<4;++j){
        float a = fmaxf(__uint_as_float(uu[j]<<16)        *A[j*2]   + Bv[j*2],   0.f);
        float d = fmaxf(__uint_as_float(uu[j]&0xffff0000u)*A[j*2+1] + Bv[j*2+1], 0.f);
        if (POOL){ ps[j*2] += a; ps[j*2+1] += d; }
        ou[j] = (unsigned)f2bfu(a) | ((unsigned)f2bfu(d)<<16);
      }
      uint4 w4; w4.x=ou[0]; w4.y=ou[1]; w4.z=ou[2]; w4.w=ou[3];
      *(uint4*)(buf + off) = w4;
    }
  }
  if (POOL){
    #pragma unroll
    for (int j=0;j<8;++j) atomicAdd(&sP[gl*8+j], ps[j]);
    __syncthreads();
    if (tid < C) atomicAdd(&pooled[tid], sP[tid]);
  }
}

// ---------------- value head MLP ----------------
__global__ void value_kernel(const float* __restrict__ pooled, const float* __restrict__ vw1,
                             const float* __restrict__ vb1, const float* __restrict__ vw2,
                             const float* __restrict__ vb2, float* __restrict__ out){
  int t = threadIdx.x;   // 64 threads
  float h = vb1[t];
  const float invN = 1.f/262144.f;
  for (int c=0;c<128;c++) h += (pooled[c]*invN)*vw1[c*64+t];
  h = fmaxf(h, 0.f);
  float v = h*vw2[t];
  #pragma unroll
  for (int off=32; off; off>>=1) v += __shfl_xor(v, off);
  if (t==0) out[262146] = v + vb2[0];
}

// ---------------- patch gather (padded NHWC, no bounds) + FC1 (1152->256), 8 cells/block ----------------
__launch_bounds__(256)
__global__ void gather_fc1_kernel(const bf16* __restrict__ f, const int* __restrict__ cell_i,
                                  const int* __restrict__ cell_j, const float* __restrict__ fw1,
                                  const float* __restrict__ fb1, float* __restrict__ h1){
  __shared__ float sF[8*1152];
  __shared__ int sij[16];
  const int tid = threadIdx.x;
  const int cellBase = blockIdx.x*8;
  if (tid < 8) sij[tid] = cell_i[cellBase+tid];
  else if (tid < 16) sij[tid] = cell_j[cellBase+tid-8];
  __syncthreads();
  for (int idx = tid; idx < 8*144; idx += 256){
    int lc = idx / 144; int rem = idx - lc*144;
    int rr = rem >> 4; int c8 = rem & 15;
    int r = rr/3, cl = rr - r*3;
    int ci = sij[lc], cj = sij[8+lc];
    uint4 v = *(const uint4*)(f + ((size_t)(ci+r)*PW + (cj+cl))*128 + c8*8);
    unsigned uu[4] = {v.x,v.y,v.z,v.w};
    float* dst = &sF[lc*1152];
    #pragma unroll
    for (int j=0;j<4;++j){
      dst[(c8*8 + j*2  )*9 + rr] = __uint_as_float(uu[j]<<16);
      dst[(c8*8 + j*2+1)*9 + rr] = __uint_as_float(uu[j]&0xffff0000u);
    }
  }
  __syncthreads();
  float acc[8];
  float bv = fb1[tid];
  #pragma unroll
  for (int lc=0;lc<8;lc++) acc[lc]=bv;
  #pragma unroll 4
  for (int k=0;k<1152;k++){
    float wv = fw1[(size_t)k*256 + tid];
    #pragma unroll
    for (int lc=0;lc<8;lc++) acc[lc] += sF[lc*1152+k]*wv;
  }
  #pragma unroll
  for (int lc=0;lc<8;lc++)
    h1[(size_t)(cellBase+lc)*256 + tid] = fmaxf(acc[lc], 0.f);
}

// ---------------- FC2 (256->128) + 3 heads + log_prob/entropy + scatter ----------------
__launch_bounds__(256)
__global__ void fc2_heads_kernel(const float* __restrict__ h1, const float* __restrict__ fw2,
                                 const float* __restrict__ fb2, const float* __restrict__ bw,
                                 const float* __restrict__ bb, const float* __restrict__ iw,
                                 const float* __restrict__ ib, const float* __restrict__ tw,
                                 const float* __restrict__ tb, const int* __restrict__ cell_i,
                                 const int* __restrict__ cell_j, const int* __restrict__ action,
                                 float* __restrict__ out){
  __shared__ float sH[8*256];
  __shared__ float sS[8*128];
  __shared__ float sRed[2];
  const int tid = threadIdx.x;
  const int cellBase = blockIdx.x*8;
  if (tid < 2) sRed[tid] = 0.f;
  for (int idx=tid; idx<2048; idx+=256) sH[idx] = h1[(size_t)cellBase*256 + idx];
  __syncthreads();
  const int j = tid & 127, half = tid >> 7;
  float acc[4];
  float bv = fb2[j];
  #pragma unroll
  for (int i=0;i<4;i++) acc[i]=bv;
  #pragma unroll 4
  for (int k=0;k<256;k++){
    float wv = fw2[k*128 + j];
    #pragma unroll
    for (int i=0;i<4;i++) acc[i] += sH[(half*4+i)*256 + k]*wv;
  }
  #pragma unroll
  for (int i=0;i<4;i++) sS[(half*4+i)*128 + j] = fmaxf(acc[i], 0.f);
  __syncthreads();
  if (tid < 96){
    int lc = tid/12, jj = tid - lc*12;
    int which = jj >> 2, o = jj & 3;
    const float* W  = (which==0) ? bw : (which==1 ? iw : tw);
    const float* Bp = (which==0) ? bb : (which==1 ? ib : tb);
    float d = Bp[o];
    for (int k=0;k<128;k++) d += sS[lc*128+k]*W[k*4+o];
    int cell = cellBase + lc;
    if (which == 1){
      out[262147 + cell*4 + o] = d;
    } else if (which == 2){
      out[262147 + 32768 + cell*4 + o] = d;
    } else {
      float p = 1.f/(1.f + __expf(-d));
      p = fminf(fmaxf(p, 1e-7f), 1.f - 1e-7f);
      int a = action[cell*4 + o];
      float lp  = a ? __logf(p) : __logf(1.f-p);
      float ent = -(p*__logf(p) + (1.f-p)*__logf(1.f-p));
      atomicAdd(&sRed[0], lp);
      atomicAdd(&sRed[1], ent);
      if (a){
        const int di[4] = {-1,0,1,0};
        const int dj[4] = {0,1,0,-1};
        int ni = cell_i[cell] + di[o];
        int nj = cell_j[cell] + dj[o];
        if ((unsigned)ni < 512u && (unsigned)nj < 512u)
          out[ni*512 + nj] = 1.0f;
      }
    }
  }
  __syncthreads();
  if (tid==0){
    atomicAdd(&out[262144], sRed[0]);
    atomicAdd(&out[262145], sRed[1]);
  }
}

extern "C" void kernel_launch(void* const* d_in, const int* in_sizes, int n_in,
                              void* d_out, int out_size, void* d_ws, size_t ws_size,
                              hipStream_t stream) {
  (void)in_sizes; (void)n_in; (void)out_size; (void)ws_size;
  const float* x      = (const float*)d_in[0];
  const int*  cell_i  = (const int*)d_in[1];
  const int*  cell_j  = (const int*)d_in[2];
  const int*  action  = (const int*)d_in[3];
  const float* w1 = (const float*)d_in[4];  const float* b1 = (const float*)d_in[5];
  const float* g1 = (const float*)d_in[6];  const float* be1= (const float*)d_in[7];
  const float* w2 = (const float*)d_in[8];  const float* b2 = (const float*)d_in[9];
  const float* g2 = (const float*)d_in[10]; const float* be2= (const float*)d_in[11];
  const float* w3 = (const float*)d_in[12]; const float* b3 = (const float*)d_in[13];
  const float* g3 = (const float*)d_in[14]; const float* be3= (const float*)d_in[15];
  const float* fw1= (const float*)d_in[16]; const float* fb1= (const float*)d_in[17];
  const float* fw2= (const float*)d_in[18]; const float* fb2= (const float*)d_in[19];
  const float* bw = (const float*)d_in[20]; const float* bb = (const float*)d_in[21];
  const float* iw = (const float*)d_in[22]; const float* ib = (const float*)d_in[23];
  const float* tw = (const float*)d_in[24]; const float* tb = (const float*)d_in[25];
  const float* vw1= (const float*)d_in[26]; const float* vb1= (const float*)d_in[27];
  const float* vw2= (const float*)d_in[28]; const float* vb2= (const float*)d_in[29];

  float* out = (float*)d_out;
  char* ws = (char*)d_ws;
  // workspace layout (bytes), padded NHWC bf16 buffers 514x514xC
  bf16* buf1 = (bf16*)(ws);                       // 25,362,816
  bf16* buf2 = (bf16*)(ws + 25362816);            // 50,725,632 -> ends 76,088,448
  bf16* bufF = (bf16*)(ws + 76088448);            // 67,634,176 -> ends 143,722,624
  bf16* wT2  = (bf16*)(ws + 143722624);           // 9*2*96*32*2  = 110,592
  bf16* wT3  = (bf16*)(ws + 143833216);           // 9*3*128*32*2 = 221,184
  float* statsf = (float*)(ws + 144054400);       // 68 floats
  float* A1 = statsf + 128; float* B1 = A1 + 48;
  float* A2 = B1 + 48;      float* B2 = A2 + 96;
  float* A3 = B2 + 96;      float* B3 = A3 + 128;
  float* pooled = B3 + 128;                       // 128 floats
  float* h1 = (float*)ws;                         // overlays buf1 (dead after conv2)

  zero_kernel<<<1025, 256, 0, stream>>>(out, statsf, pooled);
  border_zero_kernel<48> <<<(2052*6 +255)/256, 256, 0, stream>>>(buf1);
  border_zero_kernel<96> <<<(2052*12+255)/256, 256, 0, stream>>>(buf2);
  border_zero_kernel<128><<<(2052*16+255)/256, 256, 0, stream>>>(bufF);
  wtrans_kernel<96,48,2>  <<<(9*2*96*32 +255)/256, 256, 0, stream>>>(w2, wT2);
  wtrans_kernel<128,96,3> <<<(9*3*128*32+255)/256, 256, 0, stream>>>(w3, wT3);

  conv1_kernel<<<dim3(256,2), 256, 0, stream>>>(x, w1, b1, buf1);
  stats_nhwc_kernel<48><<<512, 256, 0, stream>>>(buf1, statsf + 0);
  normparam_kernel<<<1, 128, 0, stream>>>(statsf + 0, g1, be1, A1, B1, 48);
  norm_relu_kernel<48,false><<<512, 256, 0, stream>>>(buf1, A1, B1, nullptr);

  conv_mfma_kernel<48,2,3,96><<<1024, 256, 0, stream>>>(buf1, wT2, b2, buf2);
  stats_nhwc_kernel<96><<<512, 256, 0, stream>>>(buf2, statsf + 12);
  normparam_kernel<<<1, 128, 0, stream>>>(statsf + 12, g2, be2, A2, B2, 96);
  norm_relu_kernel<96,false><<<512, 256, 0, stream>>>(buf2, A2, B2, nullptr);

  conv_mfma_kernel<96,3,4,128><<<1024, 256, 0, stream>>>(buf2, wT3, b3, bufF);
  stats_nhwc_kernel<128><<<512, 256, 0, stream>>>(bufF, statsf + 36);
  normparam_kernel<<<1, 128, 0, stream>>>(statsf + 36, g3, be3, A3, B3, 128);
  norm_relu_kernel<128,true><<<512, 256, 0, stream>>>(bufF, A3, B3, pooled);

  value_kernel<<<1, 64, 0, stream>>>(pooled, vw1, vb1, vw2, vb2, out);
  gather_fc1_kernel<<<1024, 256, 0, stream>>>(bufF, cell_i, cell_j, fw1, fb1, h1);
  fc2_heads_kernel<<<1024, 256, 0, stream>>>(h1, fw2, fb2, bw, bb, iw, ib, tw, tb,
                                             cell_i, cell_j, action, out);
}

// Round 3
// 429.259 us; speedup vs baseline: 3.8705x; 1.3666x over previous
//
#include <hip/hip_runtime.h>
#include <hip/hip_bf16.h>
#include <cstddef>

#define NPIX 262144   // 512*512
#define PW 514        // padded width/height
typedef __hip_bfloat16 bf16;
typedef __attribute__((ext_vector_type(8))) short short8;
typedef __attribute__((ext_vector_type(4))) float f32x4;

__device__ inline unsigned short f2bfu(float f){
  __hip_bfloat16 h = __float2bfloat16(f);
  return *(reinterpret_cast<unsigned short*>(&h));
}
__device__ inline float bflo(unsigned u){ return __uint_as_float(u<<16); }
__device__ inline float bfhi(unsigned u){ return __uint_as_float(u & 0xffff0000u); }

// group-norm affine from accumulated stats (8 channels per group, 262144 px)
__device__ inline void computeAB(const float* stats, const float* gamma, const float* beta,
                                 int c, float& A, float& B){
  int g = c >> 3;
  const float invN = 1.f/2097152.f;
  float m = stats[g*2]*invN;
  float v = stats[g*2+1]*invN - m*m;
  float inv = rsqrtf(v + 1e-5f);
  A = inv*gamma[c];
  B = beta[c] - m*A;
}

// ---------------- zero init ----------------
__global__ void zero_kernel(float* out, float* stats, float* pooled){
  int i = blockIdx.x*256 + threadIdx.x;
  if (i < 262147) out[i] = 0.f;            // grid + log_prob + entropy + value
  if (i < 68)  stats[i]  = 0.f;            // 12 + 24 + 32 group sums/sumsq
  if (i < 128) pooled[i] = 0.f;
}

// ---------------- weight transforms ----------------
// conv2/3: OIHW fp32 -> [tap][cc32][oc][c'] bf16 (zero-pad ic)
template<int OC, int IC, int NCC>
__global__ void wtrans_kernel(const float* __restrict__ w, bf16* __restrict__ wT){
  constexpr int TOT = 9*NCC*OC*32;
  int idx = blockIdx.x*256 + threadIdx.x;
  if (idx >= TOT) return;
  int cp = idx & 31; int rest = idx >> 5;
  int oc = rest % OC; rest /= OC;
  int cc = rest % NCC; int tap = rest / NCC;
  int ic = cc*32 + cp;
  float v = (ic < IC) ? w[(oc*IC + ic)*9 + tap] : 0.f;
  wT[idx] = __float2bfloat16(v);
}
// conv1: OIHW fp32 -> [kc5][oc48][kp32] bf16; k = tap*16 + c (c padded 14->16, taps 9->10)
__global__ void wtrans1_kernel(const float* __restrict__ w, bf16* __restrict__ wT){
  int idx = blockIdx.x*256 + threadIdx.x;
  if (idx >= 5*48*32) return;
  int kp = idx & 31; int oc = (idx >> 5) % 48; int kc = idx / (48*32);
  int k = kc*32 + kp;
  int tap = k >> 4, c = k & 15;
  float v = (tap < 9 && c < 14) ? w[(oc*14 + c)*9 + tap] : 0.f;
  wT[idx] = __float2bfloat16(v);
}
// fc1: fw1 [1152][256] fp32 -> [kc36][oc256][kp32] bf16
__global__ void wtransF1_kernel(const float* __restrict__ w, bf16* __restrict__ wT){
  int idx = blockIdx.x*256 + threadIdx.x;
  if (idx >= 36*256*32) return;
  int kp = idx & 31; int oc = (idx >> 5) & 255; int kc = idx >> 13;
  wT[idx] = __float2bfloat16(w[(size_t)(kc*32 + kp)*256 + oc]);
}

// ---------------- conv1 MFMA: 14ch fp32 NCHW -> 48ch raw bf16 padded NHWC, + stats ----------------
__launch_bounds__(256,2)
__global__ void conv1_mfma_kernel(const float* __restrict__ x, const bf16* __restrict__ wT,
                                  const float* __restrict__ bias, bf16* __restrict__ out,
                                  float* __restrict__ stats){
  constexpr int XP = 24;  // px stride in shorts (16B-aligned halves, conflict-friendly)
  __shared__ unsigned short sX[324*XP];
  __shared__ float sStat[96];
  const int tid = threadIdx.x;
  const int lane = tid & 63, wave = tid >> 6;
  const int quad = lane >> 4, l15 = lane & 15;
  const int tileX = (blockIdx.x & 31)*16, tileY = (blockIdx.x >> 5)*16;
  if (tid < 96) sStat[tid] = 0.f;
  for (int p = tid; p < 324; p += 256){ sX[p*XP+14] = 0; sX[p*XP+15] = 0; }
  for (int idx = tid; idx < 14*324; idx += 256){
    int c = idx / 324, p = idx - c*324;
    int r = p / 18, col = p - r*18;
    int gy = tileY + r - 1, gx = tileX + col - 1;
    float v = 0.f;
    if ((unsigned)gy < 512u && (unsigned)gx < 512u) v = x[(size_t)c*NPIX + gy*512 + gx];
    sX[p*XP + c] = f2bfu(v);
  }
  __syncthreads();

  f32x4 acc[3][4];
  #pragma unroll
  for (int t = 0; t < 3; ++t){
    f32x4 bv = *(const f32x4*)(bias + t*16 + quad*4);
    #pragma unroll
    for (int s = 0; s < 4; ++s) acc[t][s] = bv;
  }
  const int pxb = wave*4;
  const int h = quad >> 1, chalf = (quad & 1)*8;
  const int T0[5] = {0,2,4,6,8};
  const int T1[5] = {1,3,5,7,8};   // kc=4 second tap is zero-weight; clamp addr to tap 8
  #pragma unroll
  for (int kc = 0; kc < 5; ++kc){
    short8 a[3];
    #pragma unroll
    for (int t = 0; t < 3; ++t)
      a[t] = *(const short8*)((const unsigned short*)wT + (size_t)(kc*48 + t*16 + l15)*32 + quad*8);
    const int ky = h ? (T1[kc]/3) : (T0[kc]/3);
    const int kx = h ? (T1[kc]%3) : (T0[kc]%3);
    #pragma unroll
    for (int s = 0; s < 4; ++s){
      int py = pxb + s;
      short8 b = *(const short8*)(&sX[((py+ky)*18 + l15+kx)*XP + chalf]);
      #pragma unroll
      for (int t = 0; t < 3; ++t)
        acc[t][s] = __builtin_amdgcn_mfma_f32_16x16x32_bf16(a[t], b, acc[t][s], 0, 0, 0);
    }
  }
  // stats (fp32 accs) + store raw bf16
  #pragma unroll
  for (int t = 0; t < 3; ++t){
    #pragma unroll
    for (int r = 0; r < 4; ++r){
      float sv = 0.f, sq = 0.f;
      #pragma unroll
      for (int s = 0; s < 4; ++s){ float v = acc[t][s][r]; sv += v; sq += v*v; }
      #pragma unroll
      for (int m = 1; m < 16; m <<= 1){ sv += __shfl_xor(sv, m); sq += __shfl_xor(sq, m); }
      if (l15 == 0){
        atomicAdd(&sStat[(t*16 + quad*4 + r)*2],   sv);
        atomicAdd(&sStat[(t*16 + quad*4 + r)*2+1], sq);
      }
    }
    #pragma unroll
    for (int s = 0; s < 4; ++s){
      f32x4 v = acc[t][s];
      uint2 pk;
      pk.x = (unsigned)f2bfu(v[0]) | ((unsigned)f2bfu(v[1]) << 16);
      pk.y = (unsigned)f2bfu(v[2]) | ((unsigned)f2bfu(v[3]) << 16);
      *(uint2*)(out + ((size_t)(tileY+pxb+s+1)*PW + tileX+l15+1)*48 + t*16 + quad*4) = pk;
    }
  }
  __syncthreads();
  if (tid < 12){
    int g = tid >> 1, wsel = tid & 1;
    float v = 0.f;
    #pragma unroll
    for (int j = 0; j < 8; ++j) v += sStat[(g*8+j)*2 + wsel];
    atomicAdd(&stats[g*2 + wsel], v);
  }
}

// ---------------- MFMA conv (3x3 SAME) with fused GN+ReLU on load + stats epilogue ----------------
template<int IC, int NCC, int OCT, int OC>
__launch_bounds__(256, 2)
__global__ void conv_mfma_kernel(const bf16* __restrict__ in, const bf16* __restrict__ wT,
                                 const float* __restrict__ bias,
                                 const float* __restrict__ instats, const float* __restrict__ gamma,
                                 const float* __restrict__ beta,
                                 bf16* __restrict__ out, float* __restrict__ outstats){
  constexpr int ICP = 40;                 // LDS px stride (shorts)
  __shared__ unsigned short sIn[18*18*ICP];
  __shared__ float sAB[2*IC];
  __shared__ float sStat[2*OC];
  const int tid  = threadIdx.x;
  const int lane = tid & 63, wave = tid >> 6;
  const int quad = lane >> 4, l15 = lane & 15;
  const int ocg = wave >> 1, pxg = wave & 1;
  const int tileX = (blockIdx.x & 31) * 16, tileY = (blockIdx.x >> 5) * 16;
  const int ocbase = ocg * (OCT*16);

  if (tid < IC){ float A,B; computeAB(instats, gamma, beta, tid, A, B); sAB[tid]=A; sAB[IC+tid]=B; }
  for (int i = tid; i < 2*OC; i += 256) sStat[i] = 0.f;

  f32x4 acc[OCT][8];
  #pragma unroll
  for (int t = 0; t < OCT; ++t){
    f32x4 bv = *(const f32x4*)(bias + ocbase + t*16 + quad*4);
    #pragma unroll
    for (int s = 0; s < 8; ++s) acc[t][s] = bv;
  }

  const int cc = tid & 3;
  #pragma unroll 1
  for (int cr = 0; cr < NCC; ++cr){
    __syncthreads();
    const bool chv = (cr*32 + cc*8) < IC;
    float nA[8], nB[8];
    if (chv){
      #pragma unroll
      for (int j = 0; j < 8; ++j){ nA[j] = sAB[cr*32+cc*8+j]; nB[j] = sAB[IC + cr*32+cc*8+j]; }
    }
    #pragma unroll 1
    for (int idx = tid; idx < 18*18*4; idx += 256){
      int p = idx >> 2;
      int row = p / 18, col = p - row*18;
      int gy = tileY + row, gx = tileX + col;
      uint4 v = make_uint4(0,0,0,0);
      if (chv){
        bool border = (gy==0) | (gy==513) | (gx==0) | (gx==513);
        if (!border){
          uint4 rv = *(const uint4*)(in + ((size_t)gy*PW + gx)*IC + cr*32 + cc*8);
          unsigned ru[4] = {rv.x, rv.y, rv.z, rv.w};
          unsigned ou[4];
          #pragma unroll
          for (int j = 0; j < 4; ++j){
            float a = fmaxf(bflo(ru[j])*nA[j*2]   + nB[j*2],   0.f);
            float d = fmaxf(bfhi(ru[j])*nA[j*2+1] + nB[j*2+1], 0.f);
            ou[j] = (unsigned)f2bfu(a) | ((unsigned)f2bfu(d) << 16);
          }
          v.x = ou[0]; v.y = ou[1]; v.z = ou[2]; v.w = ou[3];
        }
      }
      *(uint4*)(&sIn[p*ICP + cc*8]) = v;
    }
    __syncthreads();

    short8 a_cur[OCT], a_nxt[OCT];
    #pragma unroll
    for (int t = 0; t < OCT; ++t)
      a_cur[t] = *(const short8*)((const unsigned short*)wT + ((size_t)(0*NCC + cr)*OC + ocbase + t*16 + l15)*32 + quad*8);
    #pragma unroll 1
    for (int tap = 0; tap < 9; ++tap){
      if (tap < 8){
        #pragma unroll
        for (int t = 0; t < OCT; ++t)
          a_nxt[t] = *(const short8*)((const unsigned short*)wT + ((size_t)((tap+1)*NCC + cr)*OC + ocbase + t*16 + l15)*32 + quad*8);
      }
      const int ky = tap/3, kx = tap - ky*3;
      short8 b[8];
      #pragma unroll
      for (int s = 0; s < 8; ++s){
        int py = pxg*8 + s;
        b[s] = *(const short8*)(&sIn[((py+ky)*18 + l15+kx)*ICP + quad*8]);
      }
      #pragma unroll
      for (int s = 0; s < 8; ++s){
        #pragma unroll
        for (int t = 0; t < OCT; ++t)
          acc[t][s] = __builtin_amdgcn_mfma_f32_16x16x32_bf16(a_cur[t], b[s], acc[t][s], 0, 0, 0);
      }
      #pragma unroll
      for (int t = 0; t < OCT; ++t) a_cur[t] = a_nxt[t];
    }
  }

  // stats + store raw bf16
  #pragma unroll
  for (int t = 0; t < OCT; ++t){
    #pragma unroll
    for (int r = 0; r < 4; ++r){
      float sv = 0.f, sq = 0.f;
      #pragma unroll
      for (int s = 0; s < 8; ++s){ float v = acc[t][s][r]; sv += v; sq += v*v; }
      #pragma unroll
      for (int m = 1; m < 16; m <<= 1){ sv += __shfl_xor(sv, m); sq += __shfl_xor(sq, m); }
      if (l15 == 0){
        atomicAdd(&sStat[(ocbase + t*16 + quad*4 + r)*2],   sv);
        atomicAdd(&sStat[(ocbase + t*16 + quad*4 + r)*2+1], sq);
      }
    }
    #pragma unroll
    for (int s = 0; s < 8; ++s){
      int py = pxg*8 + s;
      f32x4 v = acc[t][s];
      uint2 pk;
      pk.x = (unsigned)f2bfu(v[0]) | ((unsigned)f2bfu(v[1]) << 16);
      pk.y = (unsigned)f2bfu(v[2]) | ((unsigned)f2bfu(v[3]) << 16);
      *(uint2*)(out + ((size_t)(tileY+py+1)*PW + (tileX+l15+1))*OC + ocbase + t*16 + quad*4) = pk;
    }
  }
  __syncthreads();
  if (tid < (OC/8)*2){
    int g = tid >> 1, wsel = tid & 1;
    float v = 0.f;
    #pragma unroll
    for (int j = 0; j < 8; ++j) v += sStat[(g*8+j)*2 + wsel];
    atomicAdd(&outstats[g*2 + wsel], v);
  }
}

// ---------------- global avg pool over normalized+ReLU f (raw bufF + in-block A,B) ----------------
__global__ void pool_kernel(const bf16* __restrict__ buf, const float* __restrict__ instats,
                            const float* __restrict__ gamma, const float* __restrict__ beta,
                            float* __restrict__ pooled){
  __shared__ float sAB[256];
  __shared__ float sP[128];
  const int tid = threadIdx.x;
  if (tid < 128){ float A,B; computeAB(instats, gamma, beta, tid, A, B);
    sAB[tid]=A; sAB[128+tid]=B; sP[tid]=0.f; }
  __syncthreads();
  const int gl = tid & 15, xl = tid >> 4;
  float A[8], B[8];
  #pragma unroll
  for (int j = 0; j < 8; ++j){ A[j] = sAB[gl*8+j]; B[j] = sAB[128+gl*8+j]; }
  const int y = blockIdx.x;
  float ps[8] = {0,0,0,0,0,0,0,0};
  for (int x = xl; x < 512; x += 16){
    uint4 v = *(const uint4*)(buf + ((size_t)(y+1)*PW + x+1)*128 + gl*8);
    unsigned uu[4] = {v.x, v.y, v.z, v.w};
    #pragma unroll
    for (int j = 0; j < 4; ++j){
      ps[j*2]   += fmaxf(bflo(uu[j])*A[j*2]   + B[j*2],   0.f);
      ps[j*2+1] += fmaxf(bfhi(uu[j])*A[j*2+1] + B[j*2+1], 0.f);
    }
  }
  #pragma unroll
  for (int j = 0; j < 8; ++j) atomicAdd(&sP[gl*8+j], ps[j]);
  __syncthreads();
  if (tid < 128) atomicAdd(&pooled[tid], sP[tid]);
}

// ---------------- value head MLP ----------------
__global__ void value_kernel(const float* __restrict__ pooled, const float* __restrict__ vw1,
                             const float* __restrict__ vb1, const float* __restrict__ vw2,
                             const float* __restrict__ vb2, float* __restrict__ out){
  int t = threadIdx.x;   // 64 threads
  float h = vb1[t];
  const float invN = 1.f/262144.f;
  for (int c = 0; c < 128; c++) h += (pooled[c]*invN)*vw1[c*64+t];
  h = fmaxf(h, 0.f);
  float v = h*vw2[t];
  #pragma unroll
  for (int off = 32; off; off >>= 1) v += __shfl_xor(v, off);
  if (t == 0) out[262146] = v + vb2[0];
}

// ---------------- gather (+GN+ReLU) + FC1 MFMA (1152->256), 32 cells/block ----------------
__launch_bounds__(256,2)
__global__ void gather_fc1_kernel(const bf16* __restrict__ f, const float* __restrict__ instats,
                                  const float* __restrict__ gamma, const float* __restrict__ beta,
                                  const int* __restrict__ cell_i, const int* __restrict__ cell_j,
                                  const bf16* __restrict__ wT, const float* __restrict__ fb1,
                                  float* __restrict__ h1){
  constexpr int KST = 1160;               // k stride (shorts): 580 dw -> 2-way bank aliasing only
  __shared__ unsigned short sG[32*KST];
  __shared__ float sAB[256];
  __shared__ int sij[64];
  const int tid = threadIdx.x;
  const int lane = tid & 63, wave = tid >> 6;
  const int quad = lane >> 4, l15 = lane & 15;
  const int cb = blockIdx.x*32;
  if (tid < 128){ float A,B; computeAB(instats, gamma, beta, tid, A, B); sAB[tid]=A; sAB[128+tid]=B; }
  if (tid < 32) sij[tid] = cell_i[cb + tid];
  else if (tid < 64) sij[tid] = cell_j[cb + tid - 32];
  __syncthreads();
  for (int idx = tid; idx < 32*144; idx += 256){
    int c8 = idx & 15; int t2 = idx >> 4;
    int cell = t2 / 9, rr = t2 - cell*9;
    int r = rr/3, cl = rr - r*3;
    int py = sij[cell] + r, px = sij[32+cell] + cl;   // padded coords
    uint4 v = *(const uint4*)(f + ((size_t)py*PW + px)*128 + c8*8);
    bool border = (py==0) | (py==513) | (px==0) | (px==513);
    unsigned uu[4] = {v.x, v.y, v.z, v.w};
    unsigned short* dst = &sG[cell*KST];
    #pragma unroll
    for (int j = 0; j < 8; ++j){
      int ch = c8*8 + j;
      float xv = (j & 1) ? bfhi(uu[j>>1]) : bflo(uu[j>>1]);
      float val = border ? 0.f : fmaxf(xv*sAB[ch] + sAB[128+ch], 0.f);
      dst[ch*9 + rr] = f2bfu(val);
    }
  }
  __syncthreads();
  f32x4 acc[4][2];
  const int ocb = wave*64;
  #pragma unroll
  for (int t = 0; t < 4; ++t){
    f32x4 bv = *(const f32x4*)(fb1 + ocb + t*16 + quad*4);
    acc[t][0] = bv; acc[t][1] = bv;
  }
  #pragma unroll 2
  for (int kc = 0; kc < 36; ++kc){
    short8 a[4], b[2];
    #pragma unroll
    for (int t = 0; t < 4; ++t)
      a[t] = *(const short8*)((const unsigned short*)wT + ((size_t)kc*256 + ocb + t*16 + l15)*32 + quad*8);
    #pragma unroll
    for (int ct = 0; ct < 2; ++ct)
      b[ct] = *(const short8*)(&sG[(ct*16 + l15)*KST + kc*32 + quad*8]);
    #pragma unroll
    for (int ct = 0; ct < 2; ++ct)
      #pragma unroll
      for (int t = 0; t < 4; ++t)
        acc[t][ct] = __builtin_amdgcn_mfma_f32_16x16x32_bf16(a[t], b[ct], acc[t][ct], 0, 0, 0);
  }
  #pragma unroll
  for (int ct = 0; ct < 2; ++ct)
    #pragma unroll
    for (int t = 0; t < 4; ++t){
      f32x4 v = acc[t][ct];
      #pragma unroll
      for (int r = 0; r < 4; ++r) v[r] = fmaxf(v[r], 0.f);
      *(f32x4*)(h1 + (size_t)(cb + ct*16 + l15)*256 + ocb + t*16 + quad*4) = v;
    }
}

// ---------------- FC2 (256->128) + 3 heads + log_prob/entropy + scatter ----------------
__launch_bounds__(256)
__global__ void fc2_heads_kernel(const float* __restrict__ h1, const float* __restrict__ fw2,
                                 const float* __restrict__ fb2, const float* __restrict__ bw,
                                 const float* __restrict__ bb, const float* __restrict__ iw,
                                 const float* __restrict__ ib, const float* __restrict__ tw,
                                 const float* __restrict__ tb, const int* __restrict__ cell_i,
                                 const int* __restrict__ cell_j, const int* __restrict__ action,
                                 float* __restrict__ out){
  __shared__ float sH[8*256];
  __shared__ float sS[8*128];
  __shared__ float sRed[2];
  const int tid = threadIdx.x;
  const int cellBase = blockIdx.x*8;
  if (tid < 2) sRed[tid] = 0.f;
  for (int idx = tid; idx < 2048; idx += 256) sH[idx] = h1[(size_t)cellBase*256 + idx];
  __syncthreads();
  const int j = tid & 127, half = tid >> 7;
  float acc[4];
  float bv = fb2[j];
  #pragma unroll
  for (int i = 0; i < 4; i++) acc[i] = bv;
  #pragma unroll 4
  for (int k = 0; k < 256; k++){
    float wv = fw2[k*128 + j];
    #pragma unroll
    for (int i = 0; i < 4; i++) acc[i] += sH[(half*4+i)*256 + k]*wv;
  }
  #pragma unroll
  for (int i = 0; i < 4; i++) sS[(half*4+i)*128 + j] = fmaxf(acc[i], 0.f);
  __syncthreads();
  if (tid < 96){
    int lc = tid/12, jj = tid - lc*12;
    int which = jj >> 2, o = jj & 3;
    const float* W  = (which==0) ? bw : (which==1 ? iw : tw);
    const float* Bp = (which==0) ? bb : (which==1 ? ib : tb);
    float d = Bp[o];
    for (int k = 0; k < 128; k++) d += sS[lc*128+k]*W[k*4+o];
    int cell = cellBase + lc;
    if (which == 1){
      out[262147 + cell*4 + o] = d;
    } else if (which == 2){
      out[262147 + 32768 + cell*4 + o] = d;
    } else {
      float p = 1.f/(1.f + __expf(-d));
      p = fminf(fmaxf(p, 1e-7f), 1.f - 1e-7f);
      int a = action[cell*4 + o];
      float lp  = a ? __logf(p) : __logf(1.f-p);
      float ent = -(p*__logf(p) + (1.f-p)*__logf(1.f-p));
      atomicAdd(&sRed[0], lp);
      atomicAdd(&sRed[1], ent);
      if (a){
        const int di[4] = {-1,0,1,0};
        const int dj[4] = {0,1,0,-1};
        int ni = cell_i[cell] + di[o];
        int nj = cell_j[cell] + dj[o];
        if ((unsigned)ni < 512u && (unsigned)nj < 512u)
          out[ni*512 + nj] = 1.0f;
      }
    }
  }
  __syncthreads();
  if (tid == 0){
    atomicAdd(&out[262144], sRed[0]);
    atomicAdd(&out[262145], sRed[1]);
  }
}

extern "C" void kernel_launch(void* const* d_in, const int* in_sizes, int n_in,
                              void* d_out, int out_size, void* d_ws, size_t ws_size,
                              hipStream_t stream) {
  (void)in_sizes; (void)n_in; (void)out_size; (void)ws_size;
  const float* x      = (const float*)d_in[0];
  const int*  cell_i  = (const int*)d_in[1];
  const int*  cell_j  = (const int*)d_in[2];
  const int*  action  = (const int*)d_in[3];
  const float* w1 = (const float*)d_in[4];  const float* b1 = (const float*)d_in[5];
  const float* g1 = (const float*)d_in[6];  const float* be1= (const float*)d_in[7];
  const float* w2 = (const float*)d_in[8];  const float* b2 = (const float*)d_in[9];
  const float* g2 = (const float*)d_in[10]; const float* be2= (const float*)d_in[11];
  const float* w3 = (const float*)d_in[12]; const float* b3 = (const float*)d_in[13];
  const float* g3 = (const float*)d_in[14]; const float* be3= (const float*)d_in[15];
  const float* fw1= (const float*)d_in[16]; const float* fb1= (const float*)d_in[17];
  const float* fw2= (const float*)d_in[18]; const float* fb2= (const float*)d_in[19];
  const float* bw = (const float*)d_in[20]; const float* bb = (const float*)d_in[21];
  const float* iw = (const float*)d_in[22]; const float* ib = (const float*)d_in[23];
  const float* tw = (const float*)d_in[24]; const float* tb = (const float*)d_in[25];
  const float* vw1= (const float*)d_in[26]; const float* vb1= (const float*)d_in[27];
  const float* vw2= (const float*)d_in[28]; const float* vb2= (const float*)d_in[29];

  float* out = (float*)d_out;
  char* ws = (char*)d_ws;
  // workspace layout (bytes), padded NHWC bf16 buffers 514x514xC (raw conv outputs)
  bf16* buf1 = (bf16*)(ws);                       // 25,362,816
  bf16* buf2 = (bf16*)(ws + 25362816);            // -> 76,088,448
  bf16* bufF = (bf16*)(ws + 76088448);            // -> 143,722,624
  bf16* wT2  = (bf16*)(ws + 143722624);           // 110,592  -> 143,833,216
  bf16* wT3  = (bf16*)(ws + 143833216);           // 221,184  -> 144,054,400
  bf16* wT1  = (bf16*)(ws + 144054400);           // 15,360   -> 144,069,760
  bf16* wF1T = (bf16*)(ws + 144069760);           // 589,824  -> 144,659,584
  float* statsf = (float*)(ws + 144659584);       // 68 floats (L1:0, L2:12, L3:36)
  float* pooled = statsf + 128;                   // 128 floats
  float* h1 = (float*)ws;                         // overlays buf1 (dead after conv2)

  zero_kernel<<<1025, 256, 0, stream>>>(out, statsf, pooled);
  wtrans1_kernel<<<(5*48*32+255)/256, 256, 0, stream>>>(w1, wT1);
  wtrans_kernel<96,48,2>  <<<(9*2*96*32 +255)/256, 256, 0, stream>>>(w2, wT2);
  wtrans_kernel<128,96,3> <<<(9*3*128*32+255)/256, 256, 0, stream>>>(w3, wT3);
  wtransF1_kernel<<<(36*256*32+255)/256, 256, 0, stream>>>(fw1, wF1T);

  conv1_mfma_kernel<<<1024, 256, 0, stream>>>(x, wT1, b1, buf1, statsf + 0);
  conv_mfma_kernel<48,2,3,96><<<1024, 256, 0, stream>>>(buf1, wT2, b2, statsf + 0, g1, be1,
                                                        buf2, statsf + 12);
  conv_mfma_kernel<96,3,4,128><<<1024, 256, 0, stream>>>(buf2, wT3, b3, statsf + 12, g2, be2,
                                                         bufF, statsf + 36);
  pool_kernel<<<512, 256, 0, stream>>>(bufF, statsf + 36, g3, be3, pooled);
  value_kernel<<<1, 64, 0, stream>>>(pooled, vw1, vb1, vw2, vb2, out);
  gather_fc1_kernel<<<256, 256, 0, stream>>>(bufF, statsf + 36, g3, be3, cell_i, cell_j,
                                             wF1T, fb1, h1);
  fc2_heads_kernel<<<1024, 256, 0, stream>>>(h1, fw2, fb2, bw, bb, iw, ib, tw, tb,
                                             cell_i, cell_j, action, out);
}

// Round 4
// 405.828 us; speedup vs baseline: 4.0939x; 1.0577x over previous
//
#include <hip/hip_runtime.h>
#include <hip/hip_bf16.h>
#include <cstddef>

#define NPIX 262144   // 512*512
#define PW 514        // padded width/height
typedef __hip_bfloat16 bf16;
typedef __attribute__((ext_vector_type(8))) short short8;
typedef __attribute__((ext_vector_type(4))) float f32x4;

__device__ inline unsigned short f2bfu(float f){
  __hip_bfloat16 h = __float2bfloat16(f);
  return *(reinterpret_cast<unsigned short*>(&h));
}
__device__ inline float bflo(unsigned u){ return __uint_as_float(u<<16); }
__device__ inline float bfhi(unsigned u){ return __uint_as_float(u & 0xffff0000u); }
// cheap pair pack: round-half-up bf16, low16=a, high16=b (values finite, no NaN here)
__device__ inline unsigned pack2bf(float a, float b){
  unsigned ua = __float_as_uint(a), ub = __float_as_uint(b);
  return ((ua + 0x8000u) >> 16) | ((ub + 0x8000u) & 0xffff0000u);
}

// group-norm affine from accumulated stats (8 channels per group, 262144 px)
__device__ inline void computeAB(const float* stats, const float* gamma, const float* beta,
                                 int c, float& A, float& B){
  int g = c >> 3;
  const float invN = 1.f/2097152.f;
  float m = stats[g*2]*invN;
  float v = stats[g*2+1]*invN - m*m;
  float inv = rsqrtf(v + 1e-5f);
  A = inv*gamma[c];
  B = beta[c] - m*A;
}

// ---------------- merged setup: zero init + all 4 weight transforms ----------------
__global__ void setup_kernel(float* out, float* stats, float* pooled,
                             const float* __restrict__ w1, bf16* __restrict__ wT1,
                             const float* __restrict__ w2, bf16* __restrict__ wT2,
                             const float* __restrict__ w3, bf16* __restrict__ wT3,
                             const float* __restrict__ fw1, bf16* __restrict__ wF1T){
  int b = blockIdx.x;
  if (b < 1025){
    int i = b*256 + threadIdx.x;
    if (i < 262147) out[i] = 0.f;            // grid + log_prob + entropy + value
    if (i < 68)  stats[i]  = 0.f;
    if (i < 128) pooled[i] = 0.f;
    return;
  }
  b -= 1025;
  if (b < 30){   // conv1 weights: [kc5][oc48][kp32], k = tap*16 + c
    int idx = b*256 + threadIdx.x;
    if (idx < 5*48*32){
      int kp = idx & 31; int oc = (idx >> 5) % 48; int kc = idx / (48*32);
      int k = kc*32 + kp;
      int tap = k >> 4, c = k & 15;
      float v = (tap < 9 && c < 14) ? w1[(oc*14 + c)*9 + tap] : 0.f;
      wT1[idx] = __float2bfloat16(v);
    }
    return;
  }
  b -= 30;
  if (b < 216){  // conv2 weights: [tap][cc2][oc96][cp32]
    int idx = b*256 + threadIdx.x;
    if (idx < 9*2*96*32){
      int cp = idx & 31; int rest = idx >> 5;
      int oc = rest % 96; rest /= 96;
      int cc = rest % 2; int tap = rest / 2;
      int ic = cc*32 + cp;
      float v = (ic < 48) ? w2[(oc*48 + ic)*9 + tap] : 0.f;
      wT2[idx] = __float2bfloat16(v);
    }
    return;
  }
  b -= 216;
  if (b < 432){  // conv3 weights: [tap][cc3][oc128][cp32]
    int idx = b*256 + threadIdx.x;
    if (idx < 9*3*128*32){
      int cp = idx & 31; int rest = idx >> 5;
      int oc = rest & 127; rest >>= 7;
      int cc = rest % 3; int tap = rest / 3;
      int ic = cc*32 + cp;
      float v = (ic < 96) ? w3[(oc*96 + ic)*9 + tap] : 0.f;
      wT3[idx] = __float2bfloat16(v);
    }
    return;
  }
  b -= 432;
  {              // fc1 weights: [kc36][oc256][kp32], k' = rr*128 + ch (tap-major)
    int idx = b*256 + threadIdx.x;
    if (idx < 36*256*32){
      int kp = idx & 31; int oc = (idx >> 5) & 255; int kc = idx >> 13;
      int k2 = kc*32 + kp;
      int rr = k2 >> 7, ch = k2 & 127;
      wF1T[idx] = __float2bfloat16(fw1[(size_t)(ch*9 + rr)*256 + oc]);
    }
  }
}

// ---------------- conv1 MFMA: 14ch fp32 NCHW -> 48ch raw bf16 padded NHWC, + stats ----------------
__launch_bounds__(256,2)
__global__ void conv1_mfma_kernel(const float* __restrict__ x, const bf16* __restrict__ wT,
                                  const float* __restrict__ bias, bf16* __restrict__ out,
                                  float* __restrict__ stats){
  constexpr int XP = 24;
  __shared__ unsigned short sX[324*XP];
  __shared__ float sStat[96];
  const int tid = threadIdx.x;
  const int lane = tid & 63, wave = tid >> 6;
  const int quad = lane >> 4, l15 = lane & 15;
  const int tileX = (blockIdx.x & 31)*16, tileY = (blockIdx.x >> 5)*16;
  if (tid < 96) sStat[tid] = 0.f;
  for (int p = tid; p < 324; p += 256){ sX[p*XP+14] = 0; sX[p*XP+15] = 0; }
  for (int idx = tid; idx < 14*324; idx += 256){
    int c = idx / 324, p = idx - c*324;
    int r = p / 18, col = p - r*18;
    int gy = tileY + r - 1, gx = tileX + col - 1;
    float v = 0.f;
    if ((unsigned)gy < 512u && (unsigned)gx < 512u) v = x[(size_t)c*NPIX + gy*512 + gx];
    sX[p*XP + c] = f2bfu(v);
  }
  __syncthreads();

  f32x4 acc[3][4];
  #pragma unroll
  for (int t = 0; t < 3; ++t){
    f32x4 bv = *(const f32x4*)(bias + t*16 + quad*4);
    #pragma unroll
    for (int s = 0; s < 4; ++s) acc[t][s] = bv;
  }
  const int pxb = wave*4;
  const int h = quad >> 1, chalf = (quad & 1)*8;
  const int T0[5] = {0,2,4,6,8};
  const int T1[5] = {1,3,5,7,8};
  #pragma unroll
  for (int kc = 0; kc < 5; ++kc){
    short8 a[3];
    #pragma unroll
    for (int t = 0; t < 3; ++t)
      a[t] = *(const short8*)((const unsigned short*)wT + (size_t)(kc*48 + t*16 + l15)*32 + quad*8);
    const int ky = h ? (T1[kc]/3) : (T0[kc]/3);
    const int kx = h ? (T1[kc]%3) : (T0[kc]%3);
    #pragma unroll
    for (int s = 0; s < 4; ++s){
      int py = pxb + s;
      short8 bfr = *(const short8*)(&sX[((py+ky)*18 + l15+kx)*XP + chalf]);
      #pragma unroll
      for (int t = 0; t < 3; ++t)
        acc[t][s] = __builtin_amdgcn_mfma_f32_16x16x32_bf16(a[t], bfr, acc[t][s], 0, 0, 0);
    }
  }
  #pragma unroll
  for (int t = 0; t < 3; ++t){
    #pragma unroll
    for (int r = 0; r < 4; ++r){
      float sv = 0.f, sq = 0.f;
      #pragma unroll
      for (int s = 0; s < 4; ++s){ float v = acc[t][s][r]; sv += v; sq += v*v; }
      #pragma unroll
      for (int m = 1; m < 16; m <<= 1){ sv += __shfl_xor(sv, m); sq += __shfl_xor(sq, m); }
      if (l15 == 0){
        atomicAdd(&sStat[(t*16 + quad*4 + r)*2],   sv);
        atomicAdd(&sStat[(t*16 + quad*4 + r)*2+1], sq);
      }
    }
    #pragma unroll
    for (int s = 0; s < 4; ++s){
      f32x4 v = acc[t][s];
      uint2 pk;
      pk.x = pack2bf(v[0], v[1]);
      pk.y = pack2bf(v[2], v[3]);
      *(uint2*)(out + ((size_t)(tileY+pxb+s+1)*PW + tileX+l15+1)*48 + t*16 + quad*4) = pk;
    }
  }
  __syncthreads();
  if (tid < 12){
    int g = tid >> 1, wsel = tid & 1;
    float v = 0.f;
    #pragma unroll
    for (int j = 0; j < 8; ++j) v += sStat[(g*8+j)*2 + wsel];
    atomicAdd(&stats[g*2 + wsel], v);
  }
}

// ---------------- MFMA conv, software-pipelined staging (prefetch next cr during MFMA) ----------------
template<int IC, int NCC, int OCT, int OC>
__launch_bounds__(256, 2)
__global__ void conv_mfma_kernel(const bf16* __restrict__ in, const bf16* __restrict__ wT,
                                 const float* __restrict__ bias,
                                 const float* __restrict__ instats, const float* __restrict__ gamma,
                                 const float* __restrict__ beta,
                                 bf16* __restrict__ out, float* __restrict__ outstats){
  constexpr int ICP = 40;
  __shared__ unsigned short sIn[18*18*ICP];
  __shared__ float sAB[2*IC];
  __shared__ float sStat[2*OC];
  const int tid  = threadIdx.x;
  const int lane = tid & 63, wave = tid >> 6;
  const int quad = lane >> 4, l15 = lane & 15;
  const int ocg = wave >> 1, pxg = wave & 1;
  const int tileX = (blockIdx.x & 31) * 16, tileY = (blockIdx.x >> 5) * 16;
  const int ocbase = ocg * (OCT*16);
  const int cc = tid & 3;

  if (tid < IC){ float A,B; computeAB(instats, gamma, beta, tid, A, B); sAB[tid]=A; sAB[IC+tid]=B; }
  for (int i = tid; i < 2*OC; i += 256) sStat[i] = 0.f;

  uint4 pref[6];
  // issue global loads for round cr into pref[]
  auto issue = [&](int cr){
    const bool chv = (cr*32 + cc*8) < IC;
    #pragma unroll
    for (int k = 0; k < 6; ++k){
      if (k == 5 && tid >= 16) continue;
      int idx = tid + k*256;
      int p = idx >> 2;
      int row = p/18, col = p - row*18;
      int gy = tileY + row, gx = tileX + col;
      bool border = (gy==0) | (gy==513) | (gx==0) | (gx==513);
      if (chv && !border)
        pref[k] = *(const uint4*)(in + ((size_t)gy*PW + gx)*IC + cr*32 + cc*8);
    }
  };
  // GN+ReLU transform pref[] -> LDS
  auto transform = [&](int cr){
    const bool chv = (cr*32 + cc*8) < IC;
    float nA[8], nB[8];
    if (chv){
      #pragma unroll
      for (int j = 0; j < 8; ++j){ nA[j] = sAB[cr*32+cc*8+j]; nB[j] = sAB[IC + cr*32+cc*8+j]; }
    }
    #pragma unroll
    for (int k = 0; k < 6; ++k){
      if (k == 5 && tid >= 16) continue;
      int idx = tid + k*256;
      int p = idx >> 2;
      int row = p/18, col = p - row*18;
      int gy = tileY + row, gx = tileX + col;
      bool border = (gy==0) | (gy==513) | (gx==0) | (gx==513);
      uint4 v = make_uint4(0,0,0,0);
      if (chv && !border){
        uint4 rv = pref[k];
        unsigned ru[4] = {rv.x, rv.y, rv.z, rv.w};
        unsigned ou[4];
        #pragma unroll
        for (int j = 0; j < 4; ++j){
          float a = fmaxf(bflo(ru[j])*nA[j*2]   + nB[j*2],   0.f);
          float d = fmaxf(bfhi(ru[j])*nA[j*2+1] + nB[j*2+1], 0.f);
          ou[j] = pack2bf(a, d);
        }
        v.x = ou[0]; v.y = ou[1]; v.z = ou[2]; v.w = ou[3];
      }
      *(uint4*)(&sIn[p*ICP + cc*8]) = v;
    }
  };

  f32x4 acc[OCT][8];
  #pragma unroll
  for (int t = 0; t < OCT; ++t){
    f32x4 bv = *(const f32x4*)(bias + ocbase + t*16 + quad*4);
    #pragma unroll
    for (int s = 0; s < 8; ++s) acc[t][s] = bv;
  }

  issue(0);
  __syncthreads();   // sAB/sStat ready

  #pragma unroll 1
  for (int cr = 0; cr < NCC; ++cr){
    transform(cr);
    __syncthreads();

    // A-frags for taps 0 and 1 issued BEFORE next-round prefetch (vmcnt FIFO ordering)
    short8 a_cur[OCT], a_nxt[OCT];
    #pragma unroll
    for (int t = 0; t < OCT; ++t)
      a_cur[t] = *(const short8*)((const unsigned short*)wT + ((size_t)(0*NCC + cr)*OC + ocbase + t*16 + l15)*32 + quad*8);
    #pragma unroll
    for (int t = 0; t < OCT; ++t)
      a_nxt[t] = *(const short8*)((const unsigned short*)wT + ((size_t)(1*NCC + cr)*OC + ocbase + t*16 + l15)*32 + quad*8);
    if (cr + 1 < NCC) issue(cr + 1);

    #pragma unroll 1
    for (int tap = 0; tap < 9; ++tap){
      const int ky = tap/3, kx = tap - ky*3;
      short8 b[8];
      #pragma unroll
      for (int s = 0; s < 8; ++s){
        int py = pxg*8 + s;
        b[s] = *(const short8*)(&sIn[((py+ky)*18 + l15+kx)*ICP + quad*8]);
      }
      #pragma unroll
      for (int s = 0; s < 8; ++s){
        #pragma unroll
        for (int t = 0; t < OCT; ++t)
          acc[t][s] = __builtin_amdgcn_mfma_f32_16x16x32_bf16(a_cur[t], b[s], acc[t][s], 0, 0, 0);
      }
      #pragma unroll
      for (int t = 0; t < OCT; ++t) a_cur[t] = a_nxt[t];
      if (tap < 7){
        #pragma unroll
        for (int t = 0; t < OCT; ++t)
          a_nxt[t] = *(const short8*)((const unsigned short*)wT + ((size_t)((tap+2)*NCC + cr)*OC + ocbase + t*16 + l15)*32 + quad*8);
      }
    }
    __syncthreads();   // protect sIn before next transform
  }

  // stats + store raw bf16
  #pragma unroll
  for (int t = 0; t < OCT; ++t){
    #pragma unroll
    for (int r = 0; r < 4; ++r){
      float sv = 0.f, sq = 0.f;
      #pragma unroll
      for (int s = 0; s < 8; ++s){ float v = acc[t][s][r]; sv += v; sq += v*v; }
      #pragma unroll
      for (int m = 1; m < 16; m <<= 1){ sv += __shfl_xor(sv, m); sq += __shfl_xor(sq, m); }
      if (l15 == 0){
        atomicAdd(&sStat[(ocbase + t*16 + quad*4 + r)*2],   sv);
        atomicAdd(&sStat[(ocbase + t*16 + quad*4 + r)*2+1], sq);
      }
    }
    #pragma unroll
    for (int s = 0; s < 8; ++s){
      int py = pxg*8 + s;
      f32x4 v = acc[t][s];
      uint2 pk;
      pk.x = pack2bf(v[0], v[1]);
      pk.y = pack2bf(v[2], v[3]);
      *(uint2*)(out + ((size_t)(tileY+py+1)*PW + (tileX+l15+1))*OC + ocbase + t*16 + quad*4) = pk;
    }
  }
  __syncthreads();
  if (tid < (OC/8)*2){
    int g = tid >> 1, wsel = tid & 1;
    float v = 0.f;
    #pragma unroll
    for (int j = 0; j < 8; ++j) v += sStat[(g*8+j)*2 + wsel];
    atomicAdd(&outstats[g*2 + wsel], v);
  }
}

// ---------------- gather (+GN+ReLU) + FC1 MFMA (32 cells/block, blocks 0..255)
//                  + global-avg-pool (blocks 256..767) ----------------
__launch_bounds__(256,2)
__global__ void gather_pool_kernel(const bf16* __restrict__ f, const float* __restrict__ instats,
                                   const float* __restrict__ gamma, const float* __restrict__ beta,
                                   const int* __restrict__ cell_i, const int* __restrict__ cell_j,
                                   const bf16* __restrict__ wT, const float* __restrict__ fb1,
                                   float* __restrict__ h1, float* __restrict__ pooled){
  constexpr int KST = 1160;               // k stride (shorts): 580 dw == 4 mod 32
  __shared__ unsigned short sG[32*KST];
  __shared__ float sAB[256];
  __shared__ int sij[64];
  __shared__ float sP[128];
  const int tid = threadIdx.x;

  if (blockIdx.x >= 256){
    // ---- pool branch ----
    if (tid < 128){ float A,B; computeAB(instats, gamma, beta, tid, A, B);
      sAB[tid]=A; sAB[128+tid]=B; sP[tid]=0.f; }
    __syncthreads();
    const int gl = tid & 15, xl = tid >> 4;
    float A[8], B[8];
    #pragma unroll
    for (int j = 0; j < 8; ++j){ A[j] = sAB[gl*8+j]; B[j] = sAB[128+gl*8+j]; }
    const int y = blockIdx.x - 256;
    float ps[8] = {0,0,0,0,0,0,0,0};
    for (int x2 = xl; x2 < 512; x2 += 16){
      uint4 v = *(const uint4*)(f + ((size_t)(y+1)*PW + x2+1)*128 + gl*8);
      unsigned uu[4] = {v.x, v.y, v.z, v.w};
      #pragma unroll
      for (int j = 0; j < 4; ++j){
        ps[j*2]   += fmaxf(bflo(uu[j])*A[j*2]   + B[j*2],   0.f);
        ps[j*2+1] += fmaxf(bfhi(uu[j])*A[j*2+1] + B[j*2+1], 0.f);
      }
    }
    #pragma unroll
    for (int j = 0; j < 8; ++j) atomicAdd(&sP[gl*8+j], ps[j]);
    __syncthreads();
    if (tid < 128) atomicAdd(&pooled[tid], sP[tid]);
    return;
  }

  // ---- gather + FC1 branch ----
  const int lane = tid & 63, wave = tid >> 6;
  const int quad = lane >> 4, l15 = lane & 15;
  const int cb = blockIdx.x*32;
  if (tid < 128){ float A,B; computeAB(instats, gamma, beta, tid, A, B); sAB[tid]=A; sAB[128+tid]=B; }
  if (tid < 32) sij[tid] = cell_i[cb + tid];
  else if (tid < 64) sij[tid] = cell_j[cb + tid - 32];
  __syncthreads();
  for (int idx = tid; idx < 32*144; idx += 256){
    int c8 = idx & 15; int t2 = idx >> 4;
    int cell = t2 / 9, rr = t2 - cell*9;
    int r = rr/3, cl = rr - r*3;
    int py = sij[cell] + r, px = sij[32+cell] + cl;   // padded coords
    uint4 v = *(const uint4*)(f + ((size_t)py*PW + px)*128 + c8*8);
    bool border = (py==0) | (py==513) | (px==0) | (px==513);
    unsigned uu[4] = {v.x, v.y, v.z, v.w};
    unsigned ou[4];
    #pragma unroll
    for (int j = 0; j < 4; ++j){
      int ch = c8*8 + j*2;
      float a = border ? 0.f : fmaxf(bflo(uu[j])*sAB[ch]   + sAB[128+ch],   0.f);
      float d = border ? 0.f : fmaxf(bfhi(uu[j])*sAB[ch+1] + sAB[128+ch+1], 0.f);
      ou[j] = pack2bf(a, d);
    }
    // k-order = rr*128 + ch (tap-major) -> contiguous 16B write
    uint4 wv; wv.x = ou[0]; wv.y = ou[1]; wv.z = ou[2]; wv.w = ou[3];
    *(uint4*)(&sG[cell*KST + rr*128 + c8*8]) = wv;
  }
  __syncthreads();
  f32x4 acc[4][2];
  const int ocb = wave*64;
  #pragma unroll
  for (int t = 0; t < 4; ++t){
    f32x4 bv = *(const f32x4*)(fb1 + ocb + t*16 + quad*4);
    acc[t][0] = bv; acc[t][1] = bv;
  }
  #pragma unroll 2
  for (int kc = 0; kc < 36; ++kc){
    short8 a[4], b[2];
    #pragma unroll
    for (int t = 0; t < 4; ++t)
      a[t] = *(const short8*)((const unsigned short*)wT + ((size_t)kc*256 + ocb + t*16 + l15)*32 + quad*8);
    #pragma unroll
    for (int ct = 0; ct < 2; ++ct)
      b[ct] = *(const short8*)(&sG[(ct*16 + l15)*KST + kc*32 + quad*8]);
    #pragma unroll
    for (int ct = 0; ct < 2; ++ct)
      #pragma unroll
      for (int t = 0; t < 4; ++t)
        acc[t][ct] = __builtin_amdgcn_mfma_f32_16x16x32_bf16(a[t], b[ct], acc[t][ct], 0, 0, 0);
  }
  #pragma unroll
  for (int ct = 0; ct < 2; ++ct)
    #pragma unroll
    for (int t = 0; t < 4; ++t){
      f32x4 v = acc[t][ct];
      #pragma unroll
      for (int r = 0; r < 4; ++r) v[r] = fmaxf(v[r], 0.f);
      *(f32x4*)(h1 + (size_t)(cb + ct*16 + l15)*256 + ocb + t*16 + quad*4) = v;
    }
}

// ---------------- FC2 + 3 heads + log_prob/entropy + scatter; block 1024 = value head ----------------
__launch_bounds__(256)
__global__ void fc2_heads_kernel(const float* __restrict__ h1, const float* __restrict__ fw2,
                                 const float* __restrict__ fb2, const float* __restrict__ bw,
                                 const float* __restrict__ bb, const float* __restrict__ iw,
                                 const float* __restrict__ ib, const float* __restrict__ tw,
                                 const float* __restrict__ tb, const int* __restrict__ cell_i,
                                 const int* __restrict__ cell_j, const int* __restrict__ action,
                                 const float* __restrict__ pooled, const float* __restrict__ vw1,
                                 const float* __restrict__ vb1, const float* __restrict__ vw2,
                                 const float* __restrict__ vb2,
                                 float* __restrict__ out){
  if (blockIdx.x == 1024){
    int t = threadIdx.x;
    if (t < 64){
      float h = vb1[t];
      const float invN = 1.f/262144.f;
      for (int c = 0; c < 128; c++) h += (pooled[c]*invN)*vw1[c*64+t];
      h = fmaxf(h, 0.f);
      float v = h*vw2[t];
      #pragma unroll
      for (int off = 32; off; off >>= 1) v += __shfl_xor(v, off);
      if (t == 0) out[262146] = v + vb2[0];
    }
    return;
  }
  __shared__ float sH[8*256];
  __shared__ float sS[8*128];
  __shared__ float sRed[2];
  const int tid = threadIdx.x;
  const int cellBase = blockIdx.x*8;
  if (tid < 2) sRed[tid] = 0.f;
  for (int idx = tid; idx < 2048; idx += 256) sH[idx] = h1[(size_t)cellBase*256 + idx];
  __syncthreads();
  const int j = tid & 127, half = tid >> 7;
  float acc[4];
  float bv = fb2[j];
  #pragma unroll
  for (int i = 0; i < 4; i++) acc[i] = bv;
  #pragma unroll 4
  for (int k = 0; k < 256; k++){
    float wv = fw2[k*128 + j];
    #pragma unroll
    for (int i = 0; i < 4; i++) acc[i] += sH[(half*4+i)*256 + k]*wv;
  }
  #pragma unroll
  for (int i = 0; i < 4; i++) sS[(half*4+i)*128 + j] = fmaxf(acc[i], 0.f);
  __syncthreads();
  if (tid < 96){
    int lc = tid/12, jj = tid - lc*12;
    int which = jj >> 2, o = jj & 3;
    const float* W  = (which==0) ? bw : (which==1 ? iw : tw);
    const float* Bp = (which==0) ? bb : (which==1 ? ib : tb);
    float d = Bp[o];
    for (int k = 0; k < 128; k++) d += sS[lc*128+k]*W[k*4+o];
    int cell = cellBase + lc;
    if (which == 1){
      out[262147 + cell*4 + o] = d;
    } else if (which == 2){
      out[262147 + 32768 + cell*4 + o] = d;
    } else {
      float p = 1.f/(1.f + __expf(-d));
      p = fminf(fmaxf(p, 1e-7f), 1.f - 1e-7f);
      int a = action[cell*4 + o];
      float lp  = a ? __logf(p) : __logf(1.f-p);
      float ent = -(p*__logf(p) + (1.f-p)*__logf(1.f-p));
      atomicAdd(&sRed[0], lp);
      atomicAdd(&sRed[1], ent);
      if (a){
        const int di[4] = {-1,0,1,0};
        const int dj[4] = {0,1,0,-1};
        int ni = cell_i[cell] + di[o];
        int nj = cell_j[cell] + dj[o];
        if ((unsigned)ni < 512u && (unsigned)nj < 512u)
          out[ni*512 + nj] = 1.0f;
      }
    }
  }
  __syncthreads();
  if (tid == 0){
    atomicAdd(&out[262144], sRed[0]);
    atomicAdd(&out[262145], sRed[1]);
  }
}

extern "C" void kernel_launch(void* const* d_in, const int* in_sizes, int n_in,
                              void* d_out, int out_size, void* d_ws, size_t ws_size,
                              hipStream_t stream) {
  (void)in_sizes; (void)n_in; (void)out_size; (void)ws_size;
  const float* x      = (const float*)d_in[0];
  const int*  cell_i  = (const int*)d_in[1];
  const int*  cell_j  = (const int*)d_in[2];
  const int*  action  = (const int*)d_in[3];
  const float* w1 = (const float*)d_in[4];  const float* b1 = (const float*)d_in[5];
  const float* g1 = (const float*)d_in[6];  const float* be1= (const float*)d_in[7];
  const float* w2 = (const float*)d_in[8];  const float* b2 = (const float*)d_in[9];
  const float* g2 = (const float*)d_in[10]; const float* be2= (const float*)d_in[11];
  const float* w3 = (const float*)d_in[12]; const float* b3 = (const float*)d_in[13];
  const float* g3 = (const float*)d_in[14]; const float* be3= (const float*)d_in[15];
  const float* fw1= (const float*)d_in[16]; const float* fb1= (const float*)d_in[17];
  const float* fw2= (const float*)d_in[18]; const float* fb2= (const float*)d_in[19];
  const float* bw = (const float*)d_in[20]; const float* bb = (const float*)d_in[21];
  const float* iw = (const float*)d_in[22]; const float* ib = (const float*)d_in[23];
  const float* tw = (const float*)d_in[24]; const float* tb = (const float*)d_in[25];
  const float* vw1= (const float*)d_in[26]; const float* vb1= (const float*)d_in[27];
  const float* vw2= (const float*)d_in[28]; const float* vb2= (const float*)d_in[29];

  float* out = (float*)d_out;
  char* ws = (char*)d_ws;
  bf16* buf1 = (bf16*)(ws);                       // 25,362,816
  bf16* buf2 = (bf16*)(ws + 25362816);            // -> 76,088,448
  bf16* bufF = (bf16*)(ws + 76088448);            // -> 143,722,624
  bf16* wT2  = (bf16*)(ws + 143722624);           // 110,592  -> 143,833,216
  bf16* wT3  = (bf16*)(ws + 143833216);           // 221,184  -> 144,054,400
  bf16* wT1  = (bf16*)(ws + 144054400);           // 15,360   -> 144,069,760
  bf16* wF1T = (bf16*)(ws + 144069760);           // 589,824  -> 144,659,584
  float* statsf = (float*)(ws + 144659584);       // 68 floats (L1:0, L2:12, L3:36)
  float* pooled = statsf + 128;                   // 128 floats
  float* h1 = (float*)ws;                         // overlays buf1 (dead after conv2)

  setup_kernel<<<2855, 256, 0, stream>>>(out, statsf, pooled, w1, wT1, w2, wT2, w3, wT3, fw1, wF1T);
  conv1_mfma_kernel<<<1024, 256, 0, stream>>>(x, wT1, b1, buf1, statsf + 0);
  conv_mfma_kernel<48,2,3,96><<<1024, 256, 0, stream>>>(buf1, wT2, b2, statsf + 0, g1, be1,
                                                        buf2, statsf + 12);
  conv_mfma_kernel<96,3,4,128><<<1024, 256, 0, stream>>>(buf2, wT3, b3, statsf + 12, g2, be2,
                                                         bufF, statsf + 36);
  gather_pool_kernel<<<768, 256, 0, stream>>>(bufF, statsf + 36, g3, be3, cell_i, cell_j,
                                              wF1T, fb1, h1, pooled);
  fc2_heads_kernel<<<1025, 256, 0, stream>>>(h1, fw2, fb2, bw, bb, iw, ib, tw, tb,
                                             cell_i, cell_j, action, pooled, vw1, vb1, vw2, vb2, out);
}

// Round 5
// 398.463 us; speedup vs baseline: 4.1696x; 1.0185x over previous
//
#include <hip/hip_runtime.h>
#include <hip/hip_bf16.h>
#include <cstddef>

#define NPIX 262144   // 512*512
#define PW 514        // padded width/height
typedef __hip_bfloat16 bf16;
typedef __attribute__((ext_vector_type(8))) short short8;
typedef __attribute__((ext_vector_type(4))) float f32x4;

__device__ inline unsigned short f2bfu(float f){
  __hip_bfloat16 h = __float2bfloat16(f);
  return *(reinterpret_cast<unsigned short*>(&h));
}
__device__ inline float bflo(unsigned u){ return __uint_as_float(u<<16); }
__device__ inline float bfhi(unsigned u){ return __uint_as_float(u & 0xffff0000u); }
// cheap pair pack: round-half-up bf16, low16=a, high16=b (values finite here)
__device__ inline unsigned pack2bf(float a, float b){
  unsigned ua = __float_as_uint(a), ub = __float_as_uint(b);
  return ((ua + 0x8000u) >> 16) | ((ub + 0x8000u) & 0xffff0000u);
}
// async global->LDS 16B DMA (wave-uniform LDS base + lane*16; gptr per-lane)
__device__ inline void dma16(const bf16* g, unsigned short* l){
  __builtin_amdgcn_global_load_lds(
      (const __attribute__((address_space(1))) unsigned int*)g,
      (__attribute__((address_space(3))) unsigned int*)l, 16, 0, 0);
}

// group-norm affine from accumulated stats (8 channels per group, 262144 px)
__device__ inline void computeAB(const float* stats, const float* gamma, const float* beta,
                                 int c, float& A, float& B){
  int g = c >> 3;
  const float invN = 1.f/2097152.f;
  float m = stats[g*2]*invN;
  float v = stats[g*2+1]*invN - m*m;
  float inv = rsqrtf(v + 1e-5f);
  A = inv*gamma[c];
  B = beta[c] - m*A;
}

// ---------------- merged setup: zero init + all 4 weight transforms ----------------
__global__ void setup_kernel(float* out, float* stats, float* pooled,
                             const float* __restrict__ w1, bf16* __restrict__ wT1,
                             const float* __restrict__ w2, bf16* __restrict__ wT2,
                             const float* __restrict__ w3, bf16* __restrict__ wT3,
                             const float* __restrict__ fw1, bf16* __restrict__ wF1T){
  int b = blockIdx.x;
  if (b < 1025){
    int i = b*256 + threadIdx.x;
    if (i < 262147) out[i] = 0.f;            // grid + log_prob + entropy + value
    if (i < 68)  stats[i]  = 0.f;
    if (i < 128) pooled[i] = 0.f;
    return;
  }
  b -= 1025;
  if (b < 30){   // conv1 weights: [kc5][oc48][kp32], k = tap*16 + c
    int idx = b*256 + threadIdx.x;
    if (idx < 5*48*32){
      int kp = idx & 31; int oc = (idx >> 5) % 48; int kc = idx / (48*32);
      int k = kc*32 + kp;
      int tap = k >> 4, c = k & 15;
      float v = (tap < 9 && c < 14) ? w1[(oc*14 + c)*9 + tap] : 0.f;
      wT1[idx] = __float2bfloat16(v);
    }
    return;
  }
  b -= 30;
  if (b < 216){  // conv2 weights: [tap][cc2][oc96][cp32] (ic 48..63 zero!)
    int idx = b*256 + threadIdx.x;
    if (idx < 9*2*96*32){
      int cp = idx & 31; int rest = idx >> 5;
      int oc = rest % 96; rest /= 96;
      int cc = rest % 2; int tap = rest / 2;
      int ic = cc*32 + cp;
      float v = (ic < 48) ? w2[(oc*48 + ic)*9 + tap] : 0.f;
      wT2[idx] = __float2bfloat16(v);
    }
    return;
  }
  b -= 216;
  if (b < 432){  // conv3 weights: [tap][cc3][oc128][cp32]
    int idx = b*256 + threadIdx.x;
    if (idx < 9*3*128*32){
      int cp = idx & 31; int rest = idx >> 5;
      int oc = rest & 127; rest >>= 7;
      int cc = rest % 3; int tap = rest / 3;
      int ic = cc*32 + cp;
      float v = (ic < 96) ? w3[(oc*96 + ic)*9 + tap] : 0.f;
      wT3[idx] = __float2bfloat16(v);
    }
    return;
  }
  b -= 432;
  {              // fc1 weights: [kc36][oc256][kp32], k' = rr*128 + ch (tap-major)
    int idx = b*256 + threadIdx.x;
    if (idx < 36*256*32){
      int kp = idx & 31; int oc = (idx >> 5) & 255; int kc = idx >> 13;
      int k2 = kc*32 + kp;
      int rr = k2 >> 7, ch = k2 & 127;
      wF1T[idx] = __float2bfloat16(fw1[(size_t)(ch*9 + rr)*256 + oc]);
    }
  }
}

// ---------------- conv1 MFMA: 14ch fp32 NCHW -> 48ch raw bf16 padded NHWC, + stats ----------------
__launch_bounds__(256,2)
__global__ void conv1_mfma_kernel(const float* __restrict__ x, const bf16* __restrict__ wT,
                                  const float* __restrict__ bias, bf16* __restrict__ out,
                                  float* __restrict__ stats){
  constexpr int XP = 24;
  __shared__ unsigned short sX[324*XP];
  __shared__ float sStat[96];
  const int tid = threadIdx.x;
  const int lane = tid & 63, wave = tid >> 6;
  const int quad = lane >> 4, l15 = lane & 15;
  const int tileX = (blockIdx.x & 31)*16, tileY = (blockIdx.x >> 5)*16;
  if (tid < 96) sStat[tid] = 0.f;
  for (int p = tid; p < 324; p += 256){ sX[p*XP+14] = 0; sX[p*XP+15] = 0; }
  for (int idx = tid; idx < 14*324; idx += 256){
    int c = idx / 324, p = idx - c*324;
    int r = p / 18, col = p - r*18;
    int gy = tileY + r - 1, gx = tileX + col - 1;
    float v = 0.f;
    if ((unsigned)gy < 512u && (unsigned)gx < 512u) v = x[(size_t)c*NPIX + gy*512 + gx];
    sX[p*XP + c] = f2bfu(v);
  }
  __syncthreads();

  f32x4 acc[3][4];
  #pragma unroll
  for (int t = 0; t < 3; ++t){
    f32x4 bv = *(const f32x4*)(bias + t*16 + quad*4);
    #pragma unroll
    for (int s = 0; s < 4; ++s) acc[t][s] = bv;
  }
  const int pxb = wave*4;
  const int h = quad >> 1, chalf = (quad & 1)*8;
  const int T0[5] = {0,2,4,6,8};
  const int T1[5] = {1,3,5,7,8};
  #pragma unroll
  for (int kc = 0; kc < 5; ++kc){
    short8 a[3];
    #pragma unroll
    for (int t = 0; t < 3; ++t)
      a[t] = *(const short8*)((const unsigned short*)wT + (size_t)(kc*48 + t*16 + l15)*32 + quad*8);
    const int ky = h ? (T1[kc]/3) : (T0[kc]/3);
    const int kx = h ? (T1[kc]%3) : (T0[kc]%3);
    #pragma unroll
    for (int s = 0; s < 4; ++s){
      int py = pxb + s;
      short8 bfr = *(const short8*)(&sX[((py+ky)*18 + l15+kx)*XP + chalf]);
      #pragma unroll
      for (int t = 0; t < 3; ++t)
        acc[t][s] = __builtin_amdgcn_mfma_f32_16x16x32_bf16(a[t], bfr, acc[t][s], 0, 0, 0);
    }
  }
  #pragma unroll
  for (int t = 0; t < 3; ++t){
    #pragma unroll
    for (int r = 0; r < 4; ++r){
      float sv = 0.f, sq = 0.f;
      #pragma unroll
      for (int s = 0; s < 4; ++s){ float v = acc[t][s][r]; sv += v; sq += v*v; }
      #pragma unroll
      for (int m = 1; m < 16; m <<= 1){ sv += __shfl_xor(sv, m); sq += __shfl_xor(sq, m); }
      if (l15 == 0){
        atomicAdd(&sStat[(t*16 + quad*4 + r)*2],   sv);
        atomicAdd(&sStat[(t*16 + quad*4 + r)*2+1], sq);
      }
    }
    #pragma unroll
    for (int s = 0; s < 4; ++s){
      f32x4 v = acc[t][s];
      uint2 pk;
      pk.x = pack2bf(v[0], v[1]);
      pk.y = pack2bf(v[2], v[3]);
      *(uint2*)(out + ((size_t)(tileY+pxb+s+1)*PW + tileX+l15+1)*48 + t*16 + quad*4) = pk;
    }
  }
  __syncthreads();
  if (tid < 12){
    int g = tid >> 1, wsel = tid & 1;
    float v = 0.f;
    #pragma unroll
    for (int j = 0; j < 8; ++j) v += sStat[(g*8+j)*2 + wsel];
    atomicAdd(&stats[g*2 + wsel], v);
  }
}

// ---------------- in-place GN+ReLU (interior) + zero borders; one block per row ----------------
template<int C>
__global__ void norm_kernel(bf16* buf, const float* __restrict__ stats,
                            const float* __restrict__ gamma, const float* __restrict__ beta){
  __shared__ float sAB[2*C];
  const int tid = threadIdx.x;
  if (tid < C){ float A,B; computeAB(stats, gamma, beta, tid, A, B); sAB[tid]=A; sAB[C+tid]=B; }
  __syncthreads();
  const int y = blockIdx.x;          // 0..513
  uint4* row = (uint4*)(buf + (size_t)y*PW*C);
  constexpr int NU = PW*C/8;         // uint4 per row (C%8==0, no px straddle)
  const bool brow = (y == 0) | (y == 513);
  for (int i = tid; i < NU; i += 256){
    int e = i*8;
    int px = e / C;
    if (brow | (px == 0) | (px == 513)){ row[i] = make_uint4(0,0,0,0); continue; }
    int ch = e - px*C;
    uint4 v = row[i];
    unsigned uu[4] = {v.x,v.y,v.z,v.w}, ou[4];
    #pragma unroll
    for (int j = 0; j < 4; ++j){
      float a = fmaxf(bflo(uu[j])*sAB[ch+j*2]   + sAB[C+ch+j*2],   0.f);
      float d = fmaxf(bfhi(uu[j])*sAB[ch+j*2+1] + sAB[C+ch+j*2+1], 0.f);
      ou[j] = pack2bf(a, d);
    }
    row[i] = make_uint4(ou[0],ou[1],ou[2],ou[3]);
  }
}

// ---------------- MFMA conv via global_load_lds DMA staging (input pre-normalized, borders 0) ----
// LDS layout: 16B slot s = (row*4 + cc)*18 + col  (row 0..17, cc = 8ch group, col 0..17)
// -> b-frag ds_read_b128 lane-stride = 4 dwords: conflict-free.
template<int IC, int NCC, int OCT, int OC>
__launch_bounds__(256, 2)
__global__ void conv_dma_kernel(const bf16* __restrict__ in, const bf16* __restrict__ wT,
                                const float* __restrict__ bias,
                                bf16* __restrict__ out, float* __restrict__ outstats){
  __shared__ unsigned short sIn[1296*8];   // 20736 B
  __shared__ float sStat[2*OC];
  const int tid  = threadIdx.x;
  const int lane = tid & 63, wave = tid >> 6;
  const int quad = lane >> 4, l15 = lane & 15;
  const int ocg = wave >> 1, pxg = wave & 1;
  const int tileX = (blockIdx.x & 31) * 16, tileY = (blockIdx.x >> 5) * 16;
  const int ocbase = ocg * (OCT*16);

  for (int i = tid; i < 2*OC; i += 256) sStat[i] = 0.f;

  f32x4 acc[OCT][8];
  #pragma unroll
  for (int t = 0; t < OCT; ++t){
    f32x4 bv = *(const f32x4*)(bias + ocbase + t*16 + quad*4);
    #pragma unroll
    for (int s = 0; s < 8; ++s) acc[t][s] = bv;
  }

  #pragma unroll 1
  for (int cr = 0; cr < NCC; ++cr){
    __syncthreads();               // sIn free from previous round
    #pragma unroll
    for (int k = 0; k < 6; ++k){
      int slot = tid + k*256;
      if (slot < 1296){
        int row = slot/72; int rem = slot - row*72;
        int cc = rem/18;   int col = rem - cc*18;
        // NOTE: for IC=48, cc>=2 in chunk cr=1 reads past-channel garbage; weights are 0 there.
        const bf16* gp = in + ((size_t)(tileY+row)*PW + tileX+col)*IC + cr*32 + cc*8;
        dma16(gp, &sIn[slot*8]);
      }
    }
    __syncthreads();               // vmcnt(0) drain: DMA complete

    short8 a_cur[OCT], a_nxt[OCT];
    #pragma unroll
    for (int t = 0; t < OCT; ++t)
      a_cur[t] = *(const short8*)((const unsigned short*)wT + ((size_t)(0*NCC + cr)*OC + ocbase + t*16 + l15)*32 + quad*8);
    #pragma unroll
    for (int t = 0; t < OCT; ++t)
      a_nxt[t] = *(const short8*)((const unsigned short*)wT + ((size_t)(1*NCC + cr)*OC + ocbase + t*16 + l15)*32 + quad*8);

    #pragma unroll 1
    for (int tap = 0; tap < 9; ++tap){
      const int ky = tap/3, kx = tap - ky*3;
      short8 b[8];
      #pragma unroll
      for (int s = 0; s < 8; ++s){
        int row = pxg*8 + s + ky;
        b[s] = *(const short8*)(&sIn[((row*4 + quad)*18 + l15 + kx)*8]);
      }
      #pragma unroll
      for (int s = 0; s < 8; ++s){
        #pragma unroll
        for (int t = 0; t < OCT; ++t)
          acc[t][s] = __builtin_amdgcn_mfma_f32_16x16x32_bf16(a_cur[t], b[s], acc[t][s], 0, 0, 0);
      }
      #pragma unroll
      for (int t = 0; t < OCT; ++t) a_cur[t] = a_nxt[t];
      if (tap < 7){
        #pragma unroll
        for (int t = 0; t < OCT; ++t)
          a_nxt[t] = *(const short8*)((const unsigned short*)wT + ((size_t)((tap+2)*NCC + cr)*OC + ocbase + t*16 + l15)*32 + quad*8);
      }
    }
  }

  // stats + store raw bf16
  #pragma unroll
  for (int t = 0; t < OCT; ++t){
    #pragma unroll
    for (int r = 0; r < 4; ++r){
      float sv = 0.f, sq = 0.f;
      #pragma unroll
      for (int s = 0; s < 8; ++s){ float v = acc[t][s][r]; sv += v; sq += v*v; }
      #pragma unroll
      for (int m = 1; m < 16; m <<= 1){ sv += __shfl_xor(sv, m); sq += __shfl_xor(sq, m); }
      if (l15 == 0){
        atomicAdd(&sStat[(ocbase + t*16 + quad*4 + r)*2],   sv);
        atomicAdd(&sStat[(ocbase + t*16 + quad*4 + r)*2+1], sq);
      }
    }
    #pragma unroll
    for (int s = 0; s < 8; ++s){
      int py = pxg*8 + s;
      f32x4 v = acc[t][s];
      uint2 pk;
      pk.x = pack2bf(v[0], v[1]);
      pk.y = pack2bf(v[2], v[3]);
      *(uint2*)(out + ((size_t)(tileY+py+1)*PW + (tileX+l15+1))*OC + ocbase + t*16 + quad*4) = pk;
    }
  }
  __syncthreads();
  if (tid < (OC/8)*2){
    int g = tid >> 1, wsel = tid & 1;
    float v = 0.f;
    #pragma unroll
    for (int j = 0; j < 8; ++j) v += sStat[(g*8+j)*2 + wsel];
    atomicAdd(&outstats[g*2 + wsel], v);
  }
}

// ---------------- gather (+GN+ReLU) + FC1 MFMA (32 cells/block, blocks 0..255)
//                  + global-avg-pool (blocks 256..767) ----------------
__launch_bounds__(256,2)
__global__ void gather_pool_kernel(const bf16* __restrict__ f, const float* __restrict__ instats,
                                   const float* __restrict__ gamma, const float* __restrict__ beta,
                                   const int* __restrict__ cell_i, const int* __restrict__ cell_j,
                                   const bf16* __restrict__ wT, const float* __restrict__ fb1,
                                   float* __restrict__ h1, float* __restrict__ pooled){
  constexpr int KST = 1160;               // k stride (shorts): 580 dw == 4 mod 32
  __shared__ unsigned short sG[32*KST];
  __shared__ float sAB[256];
  __shared__ int sij[64];
  __shared__ float sP[128];
  const int tid = threadIdx.x;

  if (blockIdx.x >= 256){
    // ---- pool branch ----
    if (tid < 128){ float A,B; computeAB(instats, gamma, beta, tid, A, B);
      sAB[tid]=A; sAB[128+tid]=B; sP[tid]=0.f; }
    __syncthreads();
    const int gl = tid & 15, xl = tid >> 4;
    float A[8], B[8];
    #pragma unroll
    for (int j = 0; j < 8; ++j){ A[j] = sAB[gl*8+j]; B[j] = sAB[128+gl*8+j]; }
    const int y = blockIdx.x - 256;
    float ps[8] = {0,0,0,0,0,0,0,0};
    for (int x2 = xl; x2 < 512; x2 += 16){
      uint4 v = *(const uint4*)(f + ((size_t)(y+1)*PW + x2+1)*128 + gl*8);
      unsigned uu[4] = {v.x, v.y, v.z, v.w};
      #pragma unroll
      for (int j = 0; j < 4; ++j){
        ps[j*2]   += fmaxf(bflo(uu[j])*A[j*2]   + B[j*2],   0.f);
        ps[j*2+1] += fmaxf(bfhi(uu[j])*A[j*2+1] + B[j*2+1], 0.f);
      }
    }
    #pragma unroll
    for (int j = 0; j < 8; ++j) atomicAdd(&sP[gl*8+j], ps[j]);
    __syncthreads();
    if (tid < 128) atomicAdd(&pooled[tid], sP[tid]);
    return;
  }

  // ---- gather + FC1 branch ----
  const int lane = tid & 63, wave = tid >> 6;
  const int quad = lane >> 4, l15 = lane & 15;
  const int cb = blockIdx.x*32;
  if (tid < 128){ float A,B; computeAB(instats, gamma, beta, tid, A, B); sAB[tid]=A; sAB[128+tid]=B; }
  if (tid < 32) sij[tid] = cell_i[cb + tid];
  else if (tid < 64) sij[tid] = cell_j[cb + tid - 32];
  __syncthreads();
  for (int idx = tid; idx < 32*144; idx += 256){
    int c8 = idx & 15; int t2 = idx >> 4;
    int cell = t2 / 9, rr = t2 - cell*9;
    int r = rr/3, cl = rr - r*3;
    int py = sij[cell] + r, px = sij[32+cell] + cl;   // padded coords
    uint4 v = *(const uint4*)(f + ((size_t)py*PW + px)*128 + c8*8);
    bool border = (py==0) | (py==513) | (px==0) | (px==513);
    unsigned uu[4] = {v.x, v.y, v.z, v.w};
    unsigned ou[4];
    #pragma unroll
    for (int j = 0; j < 4; ++j){
      int ch = c8*8 + j*2;
      float a = border ? 0.f : fmaxf(bflo(uu[j])*sAB[ch]   + sAB[128+ch],   0.f);
      float d = border ? 0.f : fmaxf(bfhi(uu[j])*sAB[ch+1] + sAB[128+ch+1], 0.f);
      ou[j] = pack2bf(a, d);
    }
    uint4 wv; wv.x = ou[0]; wv.y = ou[1]; wv.z = ou[2]; wv.w = ou[3];
    *(uint4*)(&sG[cell*KST + rr*128 + c8*8]) = wv;
  }
  __syncthreads();
  f32x4 acc[4][2];
  const int ocb = wave*64;
  #pragma unroll
  for (int t = 0; t < 4; ++t){
    f32x4 bv = *(const f32x4*)(fb1 + ocb + t*16 + quad*4);
    acc[t][0] = bv; acc[t][1] = bv;
  }
  #pragma unroll 2
  for (int kc = 0; kc < 36; ++kc){
    short8 a[4], b[2];
    #pragma unroll
    for (int t = 0; t < 4; ++t)
      a[t] = *(const short8*)((const unsigned short*)wT + ((size_t)kc*256 + ocb + t*16 + l15)*32 + quad*8);
    #pragma unroll
    for (int ct = 0; ct < 2; ++ct)
      b[ct] = *(const short8*)(&sG[(ct*16 + l15)*KST + kc*32 + quad*8]);
    #pragma unroll
    for (int ct = 0; ct < 2; ++ct)
      #pragma unroll
      for (int t = 0; t < 4; ++t)
        acc[t][ct] = __builtin_amdgcn_mfma_f32_16x16x32_bf16(a[t], b[ct], acc[t][ct], 0, 0, 0);
  }
  #pragma unroll
  for (int ct = 0; ct < 2; ++ct)
    #pragma unroll
    for (int t = 0; t < 4; ++t){
      f32x4 v = acc[t][ct];
      #pragma unroll
      for (int r = 0; r < 4; ++r) v[r] = fmaxf(v[r], 0.f);
      *(f32x4*)(h1 + (size_t)(cb + ct*16 + l15)*256 + ocb + t*16 + quad*4) = v;
    }
}

// ---------------- FC2 + 3 heads + log_prob/entropy + scatter; block 1024 = value head ----------------
__launch_bounds__(256)
__global__ void fc2_heads_kernel(const float* __restrict__ h1, const float* __restrict__ fw2,
                                 const float* __restrict__ fb2, const float* __restrict__ bw,
                                 const float* __restrict__ bb, const float* __restrict__ iw,
                                 const float* __restrict__ ib, const float* __restrict__ tw,
                                 const float* __restrict__ tb, const int* __restrict__ cell_i,
                                 const int* __restrict__ cell_j, const int* __restrict__ action,
                                 const float* __restrict__ pooled, const float* __restrict__ vw1,
                                 const float* __restrict__ vb1, const float* __restrict__ vw2,
                                 const float* __restrict__ vb2,
                                 float* __restrict__ out){
  if (blockIdx.x == 1024){
    int t = threadIdx.x;
    if (t < 64){
      float h = vb1[t];
      const float invN = 1.f/262144.f;
      for (int c = 0; c < 128; c++) h += (pooled[c]*invN)*vw1[c*64+t];
      h = fmaxf(h, 0.f);
      float v = h*vw2[t];
      #pragma unroll
      for (int off = 32; off; off >>= 1) v += __shfl_xor(v, off);
      if (t == 0) out[262146] = v + vb2[0];
    }
    return;
  }
  __shared__ float sH[8*256];
  __shared__ float sS[8*128];
  __shared__ float sRed[2];
  const int tid = threadIdx.x;
  const int cellBase = blockIdx.x*8;
  if (tid < 2) sRed[tid] = 0.f;
  for (int idx = tid; idx < 2048; idx += 256) sH[idx] = h1[(size_t)cellBase*256 + idx];
  __syncthreads();
  const int j = tid & 127, half = tid >> 7;
  float acc[4];
  float bv = fb2[j];
  #pragma unroll
  for (int i = 0; i < 4; i++) acc[i] = bv;
  #pragma unroll 4
  for (int k = 0; k < 256; k++){
    float wv = fw2[k*128 + j];
    #pragma unroll
    for (int i = 0; i < 4; i++) acc[i] += sH[(half*4+i)*256 + k]*wv;
  }
  #pragma unroll
  for (int i = 0; i < 4; i++) sS[(half*4+i)*128 + j] = fmaxf(acc[i], 0.f);
  __syncthreads();
  if (tid < 96){
    int lc = tid/12, jj = tid - lc*12;
    int which = jj >> 2, o = jj & 3;
    const float* W  = (which==0) ? bw : (which==1 ? iw : tw);
    const float* Bp = (which==0) ? bb : (which==1 ? ib : tb);
    float d = Bp[o];
    for (int k = 0; k < 128; k++) d += sS[lc*128+k]*W[k*4+o];
    int cell = cellBase + lc;
    if (which == 1){
      out[262147 + cell*4 + o] = d;
    } else if (which == 2){
      out[262147 + 32768 + cell*4 + o] = d;
    } else {
      float p = 1.f/(1.f + __expf(-d));
      p = fminf(fmaxf(p, 1e-7f), 1.f - 1e-7f);
      int a = action[cell*4 + o];
      float lp  = a ? __logf(p) : __logf(1.f-p);
      float ent = -(p*__logf(p) + (1.f-p)*__logf(1.f-p));
      atomicAdd(&sRed[0], lp);
      atomicAdd(&sRed[1], ent);
      if (a){
        const int di[4] = {-1,0,1,0};
        const int dj[4] = {0,1,0,-1};
        int ni = cell_i[cell] + di[o];
        int nj = cell_j[cell] + dj[o];
        if ((unsigned)ni < 512u && (unsigned)nj < 512u)
          out[ni*512 + nj] = 1.0f;
      }
    }
  }
  __syncthreads();
  if (tid == 0){
    atomicAdd(&out[262144], sRed[0]);
    atomicAdd(&out[262145], sRed[1]);
  }
}

extern "C" void kernel_launch(void* const* d_in, const int* in_sizes, int n_in,
                              void* d_out, int out_size, void* d_ws, size_t ws_size,
                              hipStream_t stream) {
  (void)in_sizes; (void)n_in; (void)out_size; (void)ws_size;
  const float* x      = (const float*)d_in[0];
  const int*  cell_i  = (const int*)d_in[1];
  const int*  cell_j  = (const int*)d_in[2];
  const int*  action  = (const int*)d_in[3];
  const float* w1 = (const float*)d_in[4];  const float* b1 = (const float*)d_in[5];
  const float* g1 = (const float*)d_in[6];  const float* be1= (const float*)d_in[7];
  const float* w2 = (const float*)d_in[8];  const float* b2 = (const float*)d_in[9];
  const float* g2 = (const float*)d_in[10]; const float* be2= (const float*)d_in[11];
  const float* w3 = (const float*)d_in[12]; const float* b3 = (const float*)d_in[13];
  const float* g3 = (const float*)d_in[14]; const float* be3= (const float*)d_in[15];
  const float* fw1= (const float*)d_in[16]; const float* fb1= (const float*)d_in[17];
  const float* fw2= (const float*)d_in[18]; const float* fb2= (const float*)d_in[19];
  const float* bw = (const float*)d_in[20]; const float* bb = (const float*)d_in[21];
  const float* iw = (const float*)d_in[22]; const float* ib = (const float*)d_in[23];
  const float* tw = (const float*)d_in[24]; const float* tb = (const float*)d_in[25];
  const float* vw1= (const float*)d_in[26]; const float* vb1= (const float*)d_in[27];
  const float* vw2= (const float*)d_in[28]; const float* vb2= (const float*)d_in[29];

  float* out = (float*)d_out;
  char* ws = (char*)d_ws;
  bf16* buf1 = (bf16*)(ws);                       // 25,362,816 (+slack overread ok)
  bf16* buf2 = (bf16*)(ws + 25362816);            // -> 76,088,448
  bf16* bufF = (bf16*)(ws + 76088448);            // -> 143,722,624
  bf16* wT2  = (bf16*)(ws + 143722624);           // 110,592  -> 143,833,216
  bf16* wT3  = (bf16*)(ws + 143833216);           // 221,184  -> 144,054,400
  bf16* wT1  = (bf16*)(ws + 144054400);           // 15,360   -> 144,069,760
  bf16* wF1T = (bf16*)(ws + 144069760);           // 589,824  -> 144,659,584
  float* statsf = (float*)(ws + 144659584);       // 68 floats (L1:0, L2:12, L3:36)
  float* pooled = statsf + 128;                   // 128 floats
  float* h1 = (float*)ws;                         // overlays buf1 (dead after conv2)

  setup_kernel<<<2855, 256, 0, stream>>>(out, statsf, pooled, w1, wT1, w2, wT2, w3, wT3, fw1, wF1T);
  conv1_mfma_kernel<<<1024, 256, 0, stream>>>(x, wT1, b1, buf1, statsf + 0);
  norm_kernel<48><<<514, 256, 0, stream>>>(buf1, statsf + 0, g1, be1);
  conv_dma_kernel<48,2,3,96><<<1024, 256, 0, stream>>>(buf1, wT2, b2, buf2, statsf + 12);
  norm_kernel<96><<<514, 256, 0, stream>>>(buf2, statsf + 12, g2, be2);
  conv_dma_kernel<96,3,4,128><<<1024, 256, 0, stream>>>(buf2, wT3, b3, bufF, statsf + 36);
  gather_pool_kernel<<<768, 256, 0, stream>>>(bufF, statsf + 36, g3, be3, cell_i, cell_j,
                                              wF1T, fb1, h1, pooled);
  fc2_heads_kernel<<<1025, 256, 0, stream>>>(h1, fw2, fb2, bw, bb, iw, ib, tw, tb,
                                             cell_i, cell_j, action, pooled, vw1, vb1, vw2, vb2, out);
}

// Round 6
// 378.573 us; speedup vs baseline: 4.3887x; 1.0525x over previous
//
#include <hip/hip_runtime.h>
#include <hip/hip_bf16.h>
#include <cstddef>

#define NPIX 262144   // 512*512
#define PW 514        // padded width/height
typedef __hip_bfloat16 bf16;
typedef __attribute__((ext_vector_type(8))) short short8;
typedef __attribute__((ext_vector_type(4))) float f32x4;

__device__ inline unsigned short f2bfu(float f){
  __hip_bfloat16 h = __float2bfloat16(f);
  return *(reinterpret_cast<unsigned short*>(&h));
}
__device__ inline float bflo(unsigned u){ return __uint_as_float(u<<16); }
__device__ inline float bfhi(unsigned u){ return __uint_as_float(u & 0xffff0000u); }
// cheap pair pack: round-half-up bf16, low16=a, high16=b (values finite here)
__device__ inline unsigned pack2bf(float a, float b){
  unsigned ua = __float_as_uint(a), ub = __float_as_uint(b);
  return ((ua + 0x8000u) >> 16) | ((ub + 0x8000u) & 0xffff0000u);
}
// async global->LDS 16B DMA (wave-uniform LDS base + lane*16; gptr per-lane)
__device__ inline void dma16(const bf16* g, unsigned short* l){
  __builtin_amdgcn_global_load_lds(
      (const __attribute__((address_space(1))) unsigned int*)g,
      (__attribute__((address_space(3))) unsigned int*)l, 16, 0, 0);
}

// group-norm affine from accumulated stats (8 channels per group, 262144 px)
__device__ inline void computeAB(const float* stats, const float* gamma, const float* beta,
                                 int c, float& A, float& B){
  int g = c >> 3;
  const float invN = 1.f/2097152.f;
  float m = stats[g*2]*invN;
  float v = stats[g*2+1]*invN - m*m;
  float inv = rsqrtf(v + 1e-5f);
  A = inv*gamma[c];
  B = beta[c] - m*A;
}

// ---------------- merged setup: zero init + all 5 weight transforms ----------------
__global__ void setup_kernel(float* out, float* stats, float* pooled,
                             const float* __restrict__ w1, bf16* __restrict__ wT1,
                             const float* __restrict__ w2, bf16* __restrict__ wT2,
                             const float* __restrict__ w3, bf16* __restrict__ wT3,
                             const float* __restrict__ fw1, bf16* __restrict__ wF1T,
                             const float* __restrict__ fw2, bf16* __restrict__ wF2T){
  int b = blockIdx.x;
  if (b < 1025){
    int i = b*256 + threadIdx.x;
    if (i < 262147) out[i] = 0.f;            // grid + log_prob + entropy + value
    if (i < 68)  stats[i]  = 0.f;
    if (i < 128) pooled[i] = 0.f;
    return;
  }
  b -= 1025;
  if (b < 30){   // conv1 weights: [kc5][oc48][kp32], k = tap*16 + c
    int idx = b*256 + threadIdx.x;
    if (idx < 5*48*32){
      int kp = idx & 31; int oc = (idx >> 5) % 48; int kc = idx / (48*32);
      int k = kc*32 + kp;
      int tap = k >> 4, c = k & 15;
      float v = (tap < 9 && c < 14) ? w1[(oc*14 + c)*9 + tap] : 0.f;
      wT1[idx] = __float2bfloat16(v);
    }
    return;
  }
  b -= 30;
  if (b < 216){  // conv2 weights: [tap][cc2][oc96][cp32] (ic 48..63 zero!)
    int idx = b*256 + threadIdx.x;
    if (idx < 9*2*96*32){
      int cp = idx & 31; int rest = idx >> 5;
      int oc = rest % 96; rest /= 96;
      int cc = rest % 2; int tap = rest / 2;
      int ic = cc*32 + cp;
      float v = (ic < 48) ? w2[(oc*48 + ic)*9 + tap] : 0.f;
      wT2[idx] = __float2bfloat16(v);
    }
    return;
  }
  b -= 216;
  if (b < 432){  // conv3 weights: [tap][cc3][oc128][cp32]
    int idx = b*256 + threadIdx.x;
    if (idx < 9*3*128*32){
      int cp = idx & 31; int rest = idx >> 5;
      int oc = rest & 127; rest >>= 7;
      int cc = rest % 3; int tap = rest / 3;
      int ic = cc*32 + cp;
      float v = (ic < 96) ? w3[(oc*96 + ic)*9 + tap] : 0.f;
      wT3[idx] = __float2bfloat16(v);
    }
    return;
  }
  b -= 432;
  if (b < 1152){ // fc1 weights: [kc36][oc256][kp32], k' = rr*128 + ch (tap-major)
    int idx = b*256 + threadIdx.x;
    if (idx < 36*256*32){
      int kp = idx & 31; int oc = (idx >> 5) & 255; int kc = idx >> 13;
      int k2 = kc*32 + kp;
      int rr = k2 >> 7, ch = k2 & 127;
      wF1T[idx] = __float2bfloat16(fw1[(size_t)(ch*9 + rr)*256 + oc]);
    }
    return;
  }
  b -= 1152;
  {              // fc2 weights: [kc8][oc128][kp32]
    int idx = b*256 + threadIdx.x;
    if (idx < 8*128*32){
      int kp = idx & 31; int oc = (idx >> 5) & 127; int kc = idx >> 12;
      wF2T[idx] = __float2bfloat16(fw2[(size_t)(kc*32 + kp)*128 + oc]);
    }
  }
}

// ---------------- conv1 MFMA: 14ch fp32 NCHW -> 48ch raw bf16 padded NHWC, + stats ----------------
__launch_bounds__(256,2)
__global__ void conv1_mfma_kernel(const float* __restrict__ x, const bf16* __restrict__ wT,
                                  const float* __restrict__ bias, bf16* __restrict__ out,
                                  float* __restrict__ stats){
  constexpr int XP = 24;
  __shared__ unsigned short sX[324*XP];
  __shared__ float sStat[96];
  const int tid = threadIdx.x;
  const int lane = tid & 63, wave = tid >> 6;
  const int quad = lane >> 4, l15 = lane & 15;
  const int tileX = (blockIdx.x & 31)*16, tileY = (blockIdx.x >> 5)*16;
  if (tid < 96) sStat[tid] = 0.f;
  for (int p = tid; p < 324; p += 256){ sX[p*XP+14] = 0; sX[p*XP+15] = 0; }
  for (int idx = tid; idx < 14*324; idx += 256){
    int c = idx / 324, p = idx - c*324;
    int r = p / 18, col = p - r*18;
    int gy = tileY + r - 1, gx = tileX + col - 1;
    float v = 0.f;
    if ((unsigned)gy < 512u && (unsigned)gx < 512u) v = x[(size_t)c*NPIX + gy*512 + gx];
    sX[p*XP + c] = f2bfu(v);
  }
  __syncthreads();

  f32x4 acc[3][4];
  #pragma unroll
  for (int t = 0; t < 3; ++t){
    f32x4 bv = *(const f32x4*)(bias + t*16 + quad*4);
    #pragma unroll
    for (int s = 0; s < 4; ++s) acc[t][s] = bv;
  }
  const int pxb = wave*4;
  const int h = quad >> 1, chalf = (quad & 1)*8;
  const int T0[5] = {0,2,4,6,8};
  const int T1[5] = {1,3,5,7,8};
  #pragma unroll
  for (int kc = 0; kc < 5; ++kc){
    short8 a[3];
    #pragma unroll
    for (int t = 0; t < 3; ++t)
      a[t] = *(const short8*)((const unsigned short*)wT + (size_t)(kc*48 + t*16 + l15)*32 + quad*8);
    const int ky = h ? (T1[kc]/3) : (T0[kc]/3);
    const int kx = h ? (T1[kc]%3) : (T0[kc]%3);
    #pragma unroll
    for (int s = 0; s < 4; ++s){
      int py = pxb + s;
      short8 bfr = *(const short8*)(&sX[((py+ky)*18 + l15+kx)*XP + chalf]);
      #pragma unroll
      for (int t = 0; t < 3; ++t)
        acc[t][s] = __builtin_amdgcn_mfma_f32_16x16x32_bf16(a[t], bfr, acc[t][s], 0, 0, 0);
    }
  }
  #pragma unroll
  for (int t = 0; t < 3; ++t){
    #pragma unroll
    for (int r = 0; r < 4; ++r){
      float sv = 0.f, sq = 0.f;
      #pragma unroll
      for (int s = 0; s < 4; ++s){ float v = acc[t][s][r]; sv += v; sq += v*v; }
      #pragma unroll
      for (int m = 1; m < 16; m <<= 1){ sv += __shfl_xor(sv, m); sq += __shfl_xor(sq, m); }
      if (l15 == 0){
        atomicAdd(&sStat[(t*16 + quad*4 + r)*2],   sv);
        atomicAdd(&sStat[(t*16 + quad*4 + r)*2+1], sq);
      }
    }
    #pragma unroll
    for (int s = 0; s < 4; ++s){
      f32x4 v = acc[t][s];
      uint2 pk;
      pk.x = pack2bf(v[0], v[1]);
      pk.y = pack2bf(v[2], v[3]);
      *(uint2*)(out + ((size_t)(tileY+pxb+s+1)*PW + tileX+l15+1)*48 + t*16 + quad*4) = pk;
    }
  }
  __syncthreads();
  if (tid < 12){
    int g = tid >> 1, wsel = tid & 1;
    float v = 0.f;
    #pragma unroll
    for (int j = 0; j < 8; ++j) v += sStat[(g*8+j)*2 + wsel];
    atomicAdd(&stats[g*2 + wsel], v);
  }
}

// ---------------- in-place GN+ReLU (interior) + zero borders; one block per row ----------------
template<int C>
__global__ void norm_kernel(bf16* buf, const float* __restrict__ stats,
                            const float* __restrict__ gamma, const float* __restrict__ beta){
  __shared__ float sAB[2*C];
  const int tid = threadIdx.x;
  if (tid < C){ float A,B; computeAB(stats, gamma, beta, tid, A, B); sAB[tid]=A; sAB[C+tid]=B; }
  __syncthreads();
  const int y = blockIdx.x;          // 0..513
  uint4* row = (uint4*)(buf + (size_t)y*PW*C);
  constexpr int NU = PW*C/8;         // uint4 per row (C%8==0, no px straddle)
  const bool brow = (y == 0) | (y == 513);
  for (int i = tid; i < NU; i += 256){
    int e = i*8;
    int px = e / C;
    if (brow | (px == 0) | (px == 513)){ row[i] = make_uint4(0,0,0,0); continue; }
    int ch = e - px*C;
    uint4 v = row[i];
    unsigned uu[4] = {v.x,v.y,v.z,v.w}, ou[4];
    #pragma unroll
    for (int j = 0; j < 4; ++j){
      float a = fmaxf(bflo(uu[j])*sAB[ch+j*2]   + sAB[C+ch+j*2],   0.f);
      float d = fmaxf(bfhi(uu[j])*sAB[ch+j*2+1] + sAB[C+ch+j*2+1], 0.f);
      ou[j] = pack2bf(a, d);
    }
    row[i] = make_uint4(ou[0],ou[1],ou[2],ou[3]);
  }
}

// ---------------- MFMA conv, DOUBLE-BUFFERED global_load_lds staging ----------------
// LDS layout per buffer: 16B slot s = (row*4 + cc)*18 + col
// DMA for chunk cr+1 is issued at tap 7 of chunk cr (after the chunk's last a-frag
// global load -> no in-order vmcnt stall; end-of-chunk barrier finds it ~complete).
template<int IC, int NCC, int OCT, int OC>
__launch_bounds__(256, 2)
__global__ void conv_dma_kernel(const bf16* __restrict__ in, const bf16* __restrict__ wT,
                                const float* __restrict__ bias,
                                bf16* __restrict__ out, float* __restrict__ outstats){
  __shared__ unsigned short sIn[2][1296*8];   // 2 x 20736 B
  __shared__ float sStat[2*OC];
  const int tid  = threadIdx.x;
  const int lane = tid & 63, wave = tid >> 6;
  const int quad = lane >> 4, l15 = lane & 15;
  const int ocg = wave >> 1, pxg = wave & 1;
  const int tileX = (blockIdx.x & 31) * 16, tileY = (blockIdx.x >> 5) * 16;
  const int ocbase = ocg * (OCT*16);

  for (int i = tid; i < 2*OC; i += 256) sStat[i] = 0.f;

  auto issueDMA = [&](int cr, int bi){
    #pragma unroll
    for (int k = 0; k < 6; ++k){
      int slot = tid + k*256;
      if (slot < 1296){
        int row = slot/72; int rem = slot - row*72;
        int cc = rem/18;   int col = rem - cc*18;
        // for IC=48, chunk 1 cc>=2 reads past-channel (finite) data; weights are 0 there.
        const bf16* gp = in + ((size_t)(tileY+row)*PW + tileX+col)*IC + cr*32 + cc*8;
        dma16(gp, &sIn[bi][slot*8]);
      }
    }
  };

  f32x4 acc[OCT][8];
  #pragma unroll
  for (int t = 0; t < OCT; ++t){
    f32x4 bv = *(const f32x4*)(bias + ocbase + t*16 + quad*4);
    #pragma unroll
    for (int s = 0; s < 8; ++s) acc[t][s] = bv;
  }

  issueDMA(0, 0);
  __syncthreads();               // drains DMA(0); sStat ready

  #pragma unroll 1
  for (int cr = 0; cr < NCC; ++cr){
    const unsigned short* buf = sIn[cr & 1];
    short8 a_cur[OCT], a_nxt[OCT];
    #pragma unroll
    for (int t = 0; t < OCT; ++t)
      a_cur[t] = *(const short8*)((const unsigned short*)wT + ((size_t)(0*NCC + cr)*OC + ocbase + t*16 + l15)*32 + quad*8);
    #pragma unroll
    for (int t = 0; t < OCT; ++t)
      a_nxt[t] = *(const short8*)((const unsigned short*)wT + ((size_t)(1*NCC + cr)*OC + ocbase + t*16 + l15)*32 + quad*8);

    #pragma unroll 1
    for (int tap = 0; tap < 9; ++tap){
      if (tap == 7 && cr + 1 < NCC) issueDMA(cr + 1, (cr + 1) & 1);
      const int ky = tap/3, kx = tap - ky*3;
      short8 b[8];
      #pragma unroll
      for (int s = 0; s < 8; ++s){
        int row = pxg*8 + s + ky;
        b[s] = *(const short8*)(&buf[((row*4 + quad)*18 + l15 + kx)*8]);
      }
      #pragma unroll
      for (int s = 0; s < 8; ++s){
        #pragma unroll
        for (int t = 0; t < OCT; ++t)
          acc[t][s] = __builtin_amdgcn_mfma_f32_16x16x32_bf16(a_cur[t], b[s], acc[t][s], 0, 0, 0);
      }
      #pragma unroll
      for (int t = 0; t < OCT; ++t) a_cur[t] = a_nxt[t];
      if (tap < 7){
        #pragma unroll
        for (int t = 0; t < OCT; ++t)
          a_nxt[t] = *(const short8*)((const unsigned short*)wT + ((size_t)((tap+2)*NCC + cr)*OC + ocbase + t*16 + l15)*32 + quad*8);
      }
    }
    __syncthreads();             // all waves done with buf; DMA(cr+1) drained (late-issued)
  }

  // stats + store raw bf16
  #pragma unroll
  for (int t = 0; t < OCT; ++t){
    #pragma unroll
    for (int r = 0; r < 4; ++r){
      float sv = 0.f, sq = 0.f;
      #pragma unroll
      for (int s = 0; s < 8; ++s){ float v = acc[t][s][r]; sv += v; sq += v*v; }
      #pragma unroll
      for (int m = 1; m < 16; m <<= 1){ sv += __shfl_xor(sv, m); sq += __shfl_xor(sq, m); }
      if (l15 == 0){
        atomicAdd(&sStat[(ocbase + t*16 + quad*4 + r)*2],   sv);
        atomicAdd(&sStat[(ocbase + t*16 + quad*4 + r)*2+1], sq);
      }
    }
    #pragma unroll
    for (int s = 0; s < 8; ++s){
      int py = pxg*8 + s;
      f32x4 v = acc[t][s];
      uint2 pk;
      pk.x = pack2bf(v[0], v[1]);
      pk.y = pack2bf(v[2], v[3]);
      *(uint2*)(out + ((size_t)(tileY+py+1)*PW + (tileX+l15+1))*OC + ocbase + t*16 + quad*4) = pk;
    }
  }
  __syncthreads();
  if (tid < (OC/8)*2){
    int g = tid >> 1, wsel = tid & 1;
    float v = 0.f;
    #pragma unroll
    for (int j = 0; j < 8; ++j) v += sStat[(g*8+j)*2 + wsel];
    atomicAdd(&outstats[g*2 + wsel], v);
  }
}

// ---------------- MEGA: gather+GN+ReLU -> FC1(MFMA) -> FC2(MFMA) -> heads ->
//                  log_prob/entropy/scatter, plus 2 pool rows per block. 256 blocks. ----------------
__launch_bounds__(256)
__global__ void mega_kernel(const bf16* __restrict__ f, const float* __restrict__ instats,
                            const float* __restrict__ gamma, const float* __restrict__ beta,
                            const int* __restrict__ cell_i, const int* __restrict__ cell_j,
                            const int* __restrict__ action,
                            const bf16* __restrict__ wT, const float* __restrict__ fb1,
                            const bf16* __restrict__ wT2, const float* __restrict__ fb2,
                            const float* __restrict__ bw, const float* __restrict__ bb,
                            const float* __restrict__ iw, const float* __restrict__ ib,
                            const float* __restrict__ tw, const float* __restrict__ tb,
                            float* __restrict__ pooled, float* __restrict__ out){
  constexpr int KST = 1160;               // fc1 k stride (shorts)
  __shared__ unsigned short sG[32*KST];   // 74240 B; overlaid by h2L after FC1 reads done
  __shared__ unsigned short h1L[32*264];  // 16896 B
  __shared__ float sAB[256];
  __shared__ int sij[64];
  __shared__ float sRed[2];
  __shared__ float sP[128];
  float* h2L = (float*)sG;                // 32*132 fp32 = 16896 B (inside sG)
  const int tid = threadIdx.x;
  const int lane = tid & 63, wave = tid >> 6;
  const int quad = lane >> 4, l15 = lane & 15;
  const int cb = blockIdx.x*32;

  if (tid < 2) sRed[tid] = 0.f;
  if (tid < 128){ float A,B; computeAB(instats, gamma, beta, tid, A, B);
    sAB[tid]=A; sAB[128+tid]=B; sP[tid]=0.f; }
  if (tid < 32) sij[tid] = cell_i[cb + tid];
  else if (tid < 64) sij[tid] = cell_j[cb + tid - 32];
  __syncthreads();

  // phase 1: gather 32 cells' 3x3x128 patches (GN+ReLU) -> sG [cell][k'=rr*128+ch]
  for (int idx = tid; idx < 32*144; idx += 256){
    int c8 = idx & 15; int t2 = idx >> 4;
    int cell = t2 / 9, rr = t2 - cell*9;
    int r = rr/3, cl = rr - r*3;
    int py = sij[cell] + r, px = sij[32+cell] + cl;   // padded coords
    uint4 v = *(const uint4*)(f + ((size_t)py*PW + px)*128 + c8*8);
    bool border = (py==0) | (py==513) | (px==0) | (px==513);
    unsigned uu[4] = {v.x, v.y, v.z, v.w};
    unsigned ou[4];
    #pragma unroll
    for (int j = 0; j < 4; ++j){
      int ch = c8*8 + j*2;
      float a = border ? 0.f : fmaxf(bflo(uu[j])*sAB[ch]   + sAB[128+ch],   0.f);
      float d = border ? 0.f : fmaxf(bfhi(uu[j])*sAB[ch+1] + sAB[128+ch+1], 0.f);
      ou[j] = pack2bf(a, d);
    }
    uint4 wv; wv.x = ou[0]; wv.y = ou[1]; wv.z = ou[2]; wv.w = ou[3];
    *(uint4*)(&sG[cell*KST + rr*128 + c8*8]) = wv;
  }
  __syncthreads();

  // phase 2: FC1 MFMA (1152 -> 256), wave owns oc [wave*64, wave*64+64)
  {
    f32x4 acc[4][2];
    const int ocb = wave*64;
    #pragma unroll
    for (int t = 0; t < 4; ++t){
      f32x4 bv = *(const f32x4*)(fb1 + ocb + t*16 + quad*4);
      acc[t][0] = bv; acc[t][1] = bv;
    }
    #pragma unroll 2
    for (int kc = 0; kc < 36; ++kc){
      short8 a[4], b[2];
      #pragma unroll
      for (int t = 0; t < 4; ++t)
        a[t] = *(const short8*)((const unsigned short*)wT + ((size_t)kc*256 + ocb + t*16 + l15)*32 + quad*8);
      #pragma unroll
      for (int ct = 0; ct < 2; ++ct)
        b[ct] = *(const short8*)(&sG[(ct*16 + l15)*KST + kc*32 + quad*8]);
      #pragma unroll
      for (int ct = 0; ct < 2; ++ct)
        #pragma unroll
        for (int t = 0; t < 4; ++t)
          acc[t][ct] = __builtin_amdgcn_mfma_f32_16x16x32_bf16(a[t], b[ct], acc[t][ct], 0, 0, 0);
    }
    // phase 3: relu -> bf16 -> h1L [cell][oc] stride 264
    #pragma unroll
    for (int ct = 0; ct < 2; ++ct)
      #pragma unroll
      for (int t = 0; t < 4; ++t){
        f32x4 v = acc[t][ct];
        uint2 pk;
        pk.x = pack2bf(fmaxf(v[0],0.f), fmaxf(v[1],0.f));
        pk.y = pack2bf(fmaxf(v[2],0.f), fmaxf(v[3],0.f));
        *(uint2*)(&h1L[(ct*16 + l15)*264 + ocb + t*16 + quad*4]) = pk;
      }
  }
  __syncthreads();

  // phase 4: FC2 MFMA (256 -> 128); wave: ct = w&1, oc-half = w>>1
  {
    const int ct = wave & 1, och = (wave >> 1)*64;
    f32x4 acc2[4];
    #pragma unroll
    for (int t = 0; t < 4; ++t)
      acc2[t] = *(const f32x4*)(fb2 + och + t*16 + quad*4);
    #pragma unroll
    for (int kc = 0; kc < 8; ++kc){
      short8 b = *(const short8*)(&h1L[(ct*16 + l15)*264 + kc*32 + quad*8]);
      #pragma unroll
      for (int t = 0; t < 4; ++t){
        short8 a = *(const short8*)((const unsigned short*)wT2 + ((size_t)kc*128 + och + t*16 + l15)*32 + quad*8);
        acc2[t] = __builtin_amdgcn_mfma_f32_16x16x32_bf16(a, b, acc2[t], 0, 0, 0);
      }
    }
    // phase 5: relu -> h2L fp32 [cell][oc] stride 132 (overlays sG; sG dead since phase-3 barrier)
    #pragma unroll
    for (int t = 0; t < 4; ++t){
      f32x4 v = acc2[t];
      #pragma unroll
      for (int r = 0; r < 4; ++r) v[r] = fmaxf(v[r], 0.f);
      *(f32x4*)(&h2L[(ct*16 + l15)*132 + och + t*16 + quad*4]) = v;
    }
  }
  __syncthreads();

  // phase 6: heads (32 cells x 12 outs) + log_prob/entropy/scatter
  for (int job = tid; job < 384; job += 256){
    int cell = job/12, jj = job - cell*12;
    int which = jj >> 2, o = jj & 3;
    const float* W  = (which==0) ? bw : (which==1 ? iw : tw);
    const float* Bp = (which==0) ? bb : (which==1 ? ib : tb);
    float d = Bp[o];
    const float* h2 = &h2L[cell*132];
    for (int k = 0; k < 128; k++) d += h2[k]*W[k*4+o];
    int cellg = cb + cell;
    if (which == 1){
      out[262147 + cellg*4 + o] = d;
    } else if (which == 2){
      out[262147 + 32768 + cellg*4 + o] = d;
    } else {
      float p = 1.f/(1.f + __expf(-d));
      p = fminf(fmaxf(p, 1e-7f), 1.f - 1e-7f);
      int a = action[cellg*4 + o];
      float lp  = a ? __logf(p) : __logf(1.f-p);
      float ent = -(p*__logf(p) + (1.f-p)*__logf(1.f-p));
      atomicAdd(&sRed[0], lp);
      atomicAdd(&sRed[1], ent);
      if (a){
        const int di[4] = {-1,0,1,0};
        const int dj[4] = {0,1,0,-1};
        int ni = sij[cell] + di[o];
        int nj = sij[32+cell] + dj[o];
        if ((unsigned)ni < 512u && (unsigned)nj < 512u)
          out[ni*512 + nj] = 1.0f;
      }
    }
  }

  // phase 7: global-avg-pool, 2 rows per block
  {
    const int gl = tid & 15, xl = tid >> 4;
    float A[8], B[8];
    #pragma unroll
    for (int j = 0; j < 8; ++j){ A[j] = sAB[gl*8+j]; B[j] = sAB[128+gl*8+j]; }
    #pragma unroll 1
    for (int rep = 0; rep < 2; ++rep){
      const int y = blockIdx.x + rep*256;     // 0..511
      float ps[8] = {0,0,0,0,0,0,0,0};
      for (int x2 = xl; x2 < 512; x2 += 16){
        uint4 v = *(const uint4*)(f + ((size_t)(y+1)*PW + x2+1)*128 + gl*8);
        unsigned uu[4] = {v.x, v.y, v.z, v.w};
        #pragma unroll
        for (int j = 0; j < 4; ++j){
          ps[j*2]   += fmaxf(bflo(uu[j])*A[j*2]   + B[j*2],   0.f);
          ps[j*2+1] += fmaxf(bfhi(uu[j])*A[j*2+1] + B[j*2+1], 0.f);
        }
      }
      #pragma unroll
      for (int j = 0; j < 8; ++j) atomicAdd(&sP[gl*8+j], ps[j]);
    }
  }
  __syncthreads();
  if (tid == 0){
    atomicAdd(&out[262144], sRed[0]);
    atomicAdd(&out[262145], sRed[1]);
  }
  if (tid < 128) atomicAdd(&pooled[tid], sP[tid]);
}

// ---------------- value head MLP ----------------
__global__ void value_kernel(const float* __restrict__ pooled, const float* __restrict__ vw1,
                             const float* __restrict__ vb1, const float* __restrict__ vw2,
                             const float* __restrict__ vb2, float* __restrict__ out){
  int t = threadIdx.x;   // 64 threads
  float h = vb1[t];
  const float invN = 1.f/262144.f;
  for (int c = 0; c < 128; c++) h += (pooled[c]*invN)*vw1[c*64+t];
  h = fmaxf(h, 0.f);
  float v = h*vw2[t];
  #pragma unroll
  for (int off = 32; off; off >>= 1) v += __shfl_xor(v, off);
  if (t == 0) out[262146] = v + vb2[0];
}

extern "C" void kernel_launch(void* const* d_in, const int* in_sizes, int n_in,
                              void* d_out, int out_size, void* d_ws, size_t ws_size,
                              hipStream_t stream) {
  (void)in_sizes; (void)n_in; (void)out_size; (void)ws_size;
  const float* x      = (const float*)d_in[0];
  const int*  cell_i  = (const int*)d_in[1];
  const int*  cell_j  = (const int*)d_in[2];
  const int*  action  = (const int*)d_in[3];
  const float* w1 = (const float*)d_in[4];  const float* b1 = (const float*)d_in[5];
  const float* g1 = (const float*)d_in[6];  const float* be1= (const float*)d_in[7];
  const float* w2 = (const float*)d_in[8];  const float* b2 = (const float*)d_in[9];
  const float* g2 = (const float*)d_in[10]; const float* be2= (const float*)d_in[11];
  const float* w3 = (const float*)d_in[12]; const float* b3 = (const float*)d_in[13];
  const float* g3 = (const float*)d_in[14]; const float* be3= (const float*)d_in[15];
  const float* fw1= (const float*)d_in[16]; const float* fb1= (const float*)d_in[17];
  const float* fw2= (const float*)d_in[18]; const float* fb2= (const float*)d_in[19];
  const float* bw = (const float*)d_in[20]; const float* bb = (const float*)d_in[21];
  const float* iw = (const float*)d_in[22]; const float* ib = (const float*)d_in[23];
  const float* tw = (const float*)d_in[24]; const float* tb = (const float*)d_in[25];
  const float* vw1= (const float*)d_in[26]; const float* vb1= (const float*)d_in[27];
  const float* vw2= (const float*)d_in[28]; const float* vb2= (const float*)d_in[29];

  float* out = (float*)d_out;
  char* ws = (char*)d_ws;
  bf16* buf1 = (bf16*)(ws);                       // 25,362,816 (+30B overread slack into buf2)
  bf16* buf2 = (bf16*)(ws + 25362816);            // -> 76,088,448
  bf16* bufF = (bf16*)(ws + 76088448);            // -> 143,722,624
  bf16* wT2  = (bf16*)(ws + 143722624);           // 110,592  -> 143,833,216
  bf16* wT3  = (bf16*)(ws + 143833216);           // 221,184  -> 144,054,400
  bf16* wT1  = (bf16*)(ws + 144054400);           // 15,360   -> 144,069,760
  bf16* wF1T = (bf16*)(ws + 144069760);           // 589,824  -> 144,659,584
  bf16* wF2T = (bf16*)(ws + 144659584);           // 65,536   -> 144,725,120
  float* statsf = (float*)(ws + 144725120);       // 68 floats (L1:0, L2:12, L3:36)
  float* pooled = statsf + 128;                   // 128 floats

  setup_kernel<<<2983, 256, 0, stream>>>(out, statsf, pooled, w1, wT1, w2, wT2, w3, wT3,
                                         fw1, wF1T, fw2, wF2T);
  conv1_mfma_kernel<<<1024, 256, 0, stream>>>(x, wT1, b1, buf1, statsf + 0);
  norm_kernel<48><<<514, 256, 0, stream>>>(buf1, statsf + 0, g1, be1);
  conv_dma_kernel<48,2,3,96><<<1024, 256, 0, stream>>>(buf1, wT2, b2, buf2, statsf + 12);
  norm_kernel<96><<<514, 256, 0, stream>>>(buf2, statsf + 12, g2, be2);
  conv_dma_kernel<96,3,4,128><<<1024, 256, 0, stream>>>(buf2, wT3, b3, bufF, statsf + 36);
  mega_kernel<<<256, 256, 0, stream>>>(bufF, statsf + 36, g3, be3, cell_i, cell_j, action,
                                       wF1T, fb1, wF2T, fb2, bw, bb, iw, ib, tw, tb,
                                       pooled, out);
  value_kernel<<<1, 64, 0, stream>>>(pooled, vw1, vb1, vw2, vb2, out);
}